// Round 1
// baseline (5215.998 us; speedup 1.0000x reference)
//
#include <hip/hip_runtime.h>
#include <math.h>

// Problem constants
#define B_   2
#define L_   4096
#define DI_  128

// -------- workspace layout (float offsets), stage-lifetime aliased --------
// R1 [0, 12,582,912): xc2 / xc2T (stages 3-4)  -> ys_t (stages 5-6)
static constexpr int OFF_XC2  = 0;                      // 3*B*128*L
static constexpr int OFF_XC2T = 3145728;                // 3*B*128*L
static constexpr int OFF_YS   = 0;                      // 3*B*4*L*128
// R2 [12,582,912, 16,515,072): xc (2-3) -> bc_t (4-5)  (3*B*4*L*40)
static constexpr int OFF_XC   = 12582912;
static constexpr int OFF_BC   = 12582912;
// R3 [16,515,072, 22,806,528): xs_t (4-5) -> attention buffers (7-10)
static constexpr int OFF_XS   = 16515072;               // 3*B*2*L*128
static constexpr int OFF_Q    = 16515072;
static constexpr int OFF_K1   = 16515072 +  524288;
static constexpr int OFF_K2   = 16515072 + 1048576;
static constexpr int OFF_V    = 16515072 + 1572864;
static constexpr int OFF_O1   = 16515072 + 2097152;
static constexpr int OFF_O2   = 16515072 + 2621440;
static constexpr int OFF_RAW  = 16515072 + 3145728;
static constexpr int OFF_ST   = 16515072 + 3670016;
// R4: feats (1-6)
static constexpr int OFF_FE   = 22806528;               // 3*B*64*L
// R5: z (2-6)
static constexpr int OFF_Z    = 24379392;               // 3*B*128*L
// R6: vss_out (6-9)
static constexpr int OFF_VSS  = 27525120;               // 3*B*64*L
// R7: transposed weights
static constexpr int OFF_AWT1 = 29097984;
static constexpr int OFF_AWT2 = 29097984 + 8192;
static constexpr int OFF_AWT3 = 29097984 + 24576;
static constexpr int OFF_PWT  = 29097984 + 57344;
// total: 29,167,616 floats = 116.7 MB

// ---------------- weight transposes ----------------
__global__ void __launch_bounds__(256) pex_prep(
    const float* __restrict__ aw1, const float* __restrict__ aw2,
    const float* __restrict__ aw3, const float* __restrict__ pw,
    float* __restrict__ ws)
{
    int idx = blockIdx.x * 256 + threadIdx.x;   // 32768 total
    int ic = idx >> 6, c = idx & 63;
    if (ic < 128) ws[OFF_AWT1 + idx] = aw1[c * 128 + ic];
    if (ic < 256) ws[OFF_AWT2 + idx] = aw2[c * 256 + ic];
    ws[OFF_AWT3 + idx] = aw3[c * 512 + ic];
    if (idx < 192 * 64) {
        int cp = idx >> 6;
        ws[OFF_PWT + idx] = pw[c * 192 + cp];
    }
}

// ---------------- stage 1: feats = conv1x1(x_i) ----------------
__global__ void __launch_bounds__(256) pex_feats(
    const float* __restrict__ x1, const float* __restrict__ x2, const float* __restrict__ x3,
    const float* __restrict__ ab1, const float* __restrict__ ab2, const float* __restrict__ ab3,
    float* __restrict__ ws)
{
    int bid = blockIdx.x;            // i*32 + b*16 + pt
    int i = bid >> 5;
    int r = bid & 31;
    int b = r >> 4;
    int p = (r & 15) * 256 + threadIdx.x;
    int c0 = blockIdx.y * 32;
    const float* xp; const float* ab; const float* awT; int IC;
    if (i == 0)      { xp = x1; ab = ab1; awT = ws + OFF_AWT1; IC = 128; }
    else if (i == 1) { xp = x2; ab = ab2; awT = ws + OFF_AWT2; IC = 256; }
    else             { xp = x3; ab = ab3; awT = ws + OFF_AWT3; IC = 512; }
    xp += (size_t)b * IC * L_ + p;
    float acc[32];
#pragma unroll
    for (int c = 0; c < 32; ++c) acc[c] = ab[c0 + c];
    for (int ic = 0; ic < IC; ++ic) {
        float v = xp[(size_t)ic * L_];
        const float4* wr = (const float4*)(awT + ic * 64 + c0);
#pragma unroll
        for (int j = 0; j < 8; ++j) {
            float4 w = wr[j];
            acc[j*4+0] = fmaf(v, w.x, acc[j*4+0]);
            acc[j*4+1] = fmaf(v, w.y, acc[j*4+1]);
            acc[j*4+2] = fmaf(v, w.z, acc[j*4+2]);
            acc[j*4+3] = fmaf(v, w.w, acc[j*4+3]);
        }
    }
    float* fe = ws + OFF_FE + ((size_t)(i * B_ + b) * 64 + c0) * L_ + p;
#pragma unroll
    for (int c = 0; c < 32; ++c) fe[(size_t)c * L_] = acc[c];
}

// ---------------- stage 2: pixel-exchange gather + LN + in_proj ----------------
// y=0 -> xc (oc 0..127, NCHW), y=1 -> z (oc 128..255, (i,b,d,L))
__global__ void __launch_bounds__(256) pex_lnproj(
    const float* __restrict__ lng, const float* __restrict__ lnb,
    const float* __restrict__ inw, const float* __restrict__ inb,
    float* __restrict__ ws)
{
    int bid = blockIdx.x;
    int i = bid >> 5;
    int r = bid & 31;
    int b = r >> 4;
    int p = (r & 15) * 256 + threadIdx.x;
    int h = p >> 6, w = p & 63;
    int src = (i + h % 3 + w % 3) % 3;
    const float* fe = ws + OFF_FE + (size_t)(src * B_ + b) * 64 * L_ + p;
    float f[64];
    float s = 0.f;
#pragma unroll
    for (int c = 0; c < 64; ++c) { f[c] = fe[(size_t)c * L_]; s += f[c]; }
    float mean = s * (1.f / 64.f);
    float vs = 0.f;
#pragma unroll
    for (int c = 0; c < 64; ++c) { float d = f[c] - mean; vs = fmaf(d, d, vs); }
    float rs = rsqrtf(vs * (1.f / 64.f) + 1e-5f);
#pragma unroll
    for (int c = 0; c < 64; ++c)
        f[c] = (f[c] - mean) * rs * lng[i * 64 + c] + lnb[i * 64 + c];

    int oc0 = blockIdx.y * 128;
    const float* wbase = inw + (size_t)i * 256 * 64;
    float* outp = (blockIdx.y == 0)
        ? (ws + OFF_XC + (size_t)(i * B_ + b) * DI_ * L_ + p)
        : (ws + OFF_Z  + (size_t)(i * B_ + b) * DI_ * L_ + p);
    for (int oc = 0; oc < 128; ++oc) {
        int oca = oc0 + oc;
        const float4* wr = (const float4*)(wbase + oca * 64);
        float acc = inb[i * 256 + oca];
#pragma unroll
        for (int j = 0; j < 16; ++j) {
            float4 w = wr[j];
            acc = fmaf(f[j*4+0], w.x, acc);
            acc = fmaf(f[j*4+1], w.y, acc);
            acc = fmaf(f[j*4+2], w.z, acc);
            acc = fmaf(f[j*4+3], w.w, acc);
        }
        outp[(size_t)oc * L_] = acc;
    }
}

// ---------------- stage 3: depthwise 3x3 conv + SiLU, write HW and WH layouts ----------------
__global__ void __launch_bounds__(256) pex_conv(
    const float* __restrict__ cw, const float* __restrict__ cb, float* __restrict__ ws)
{
    __shared__ float sm[64 * 65];
    int bid = blockIdx.x;          // i*256 + b*128 + d
    int i = bid >> 8;
    int r = bid & 255;
    int b = r >> 7;
    int d = r & 127;
    float wk[9];
#pragma unroll
    for (int j = 0; j < 9; ++j) wk[j] = cw[(size_t)(i * DI_ + d) * 9 + j];
    float bias = cb[i * DI_ + d];
    const float* xin = ws + OFF_XC + ((size_t)(i * B_ + b) * DI_ + d) * L_;
    float* xo  = ws + OFF_XC2  + ((size_t)(i * B_ + b) * DI_ + d) * L_;
    float* xoT = ws + OFF_XC2T + ((size_t)(i * B_ + b) * DI_ + d) * L_;
#pragma unroll
    for (int j = 0; j < 16; ++j) {
        int p = j * 256 + threadIdx.x;
        int h = p >> 6, w = p & 63;
        float acc = bias;
#pragma unroll
        for (int dh = 0; dh < 3; ++dh) {
            int hh = h + dh - 1;
            if (hh < 0 || hh > 63) continue;
#pragma unroll
            for (int dw = 0; dw < 3; ++dw) {
                int ww = w + dw - 1;
                if (ww < 0 || ww > 63) continue;
                acc = fmaf(xin[hh * 64 + ww], wk[dh * 3 + dw], acc);
            }
        }
        float v = acc / (1.f + __expf(-acc));
        xo[p] = v;
        sm[h * 65 + w] = v;
    }
    __syncthreads();
#pragma unroll
    for (int j = 0; j < 16; ++j) {
        int q = j * 256 + threadIdx.x;
        int h = q & 63, w = q >> 6;       // q = w*64 + h
        xoT[q] = sm[h * 65 + w];
    }
}

// ---------------- stage 4a: transpose to t-major xs_t (ks=0 from xc2, ks=1 from xc2T) ----------------
__global__ void __launch_bounds__(256) pex_xst(float* __restrict__ ws)
{
    __shared__ float sm[64 * 65];
    int bid = blockIdx.x;            // ibk*128 + dt*64 + tt
    int tt = bid & 63;
    int dt = (bid >> 6) & 1;
    int ibk = bid >> 7;              // (i*B+b)*2 + ks, 0..11
    int ks = ibk & 1, ib = ibk >> 1;
    const float* src = ws + (ks ? OFF_XC2T : OFF_XC2)
                     + ((size_t)ib * DI_ + dt * 64) * L_ + tt * 64;
#pragma unroll
    for (int j = 0; j < 16; ++j) {
        int idx = j * 256 + threadIdx.x;
        int dl = idx >> 6, tl = idx & 63;
        sm[dl * 65 + tl] = src[(size_t)dl * L_ + tl];
    }
    __syncthreads();
    float* dst = ws + OFF_XS + ((size_t)ibk * L_ + tt * 64) * DI_ + dt * 64;
#pragma unroll
    for (int j = 0; j < 16; ++j) {
        int idx = j * 256 + threadIdx.x;
        int tl = idx >> 6, dl = idx & 63;
        dst[(size_t)tl * DI_ + dl] = sm[dl * 65 + tl];
    }
}

// ---------------- stage 4b: x_dbl -> bc_t (r[4], B[16], C[16], pad to 40) ----------------
__global__ void __launch_bounds__(256) pex_bct(
    const float* __restrict__ xpw, float* __restrict__ ws)
{
    int bid = blockIdx.x;            // ibk*16 + tt
    int tt = bid & 15;
    int ibk = bid >> 4;              // (i*B+b)*4 + k
    int k = ibk & 3;
    int ib = ibk >> 2;
    int i = ib >> 1;
    int t = tt * 256 + threadIdx.x;
    int ks = k & 1;
    int tx = (k >= 2) ? (L_ - 1 - t) : t;
    const float4* xr = (const float4*)(ws + OFF_XS + ((size_t)(ib * 2 + ks) * L_ + tx) * DI_);
    float4 xv[32];
#pragma unroll
    for (int j = 0; j < 32; ++j) xv[j] = xr[j];
    float* out = ws + OFF_BC + ((size_t)ibk * L_ + t) * 40;
    const float* wb = xpw + (size_t)(i * 4 + k) * 36 * DI_;
    for (int c = 0; c < 36; ++c) {
        const float4* wr = (const float4*)(wb + c * DI_);
        float acc = 0.f;
#pragma unroll
        for (int j = 0; j < 32; ++j) {
            float4 w = wr[j];
            acc = fmaf(xv[j].x, w.x, acc);
            acc = fmaf(xv[j].y, w.y, acc);
            acc = fmaf(xv[j].z, w.z, acc);
            acc = fmaf(xv[j].w, w.w, acc);
        }
        out[c] = acc;
    }
}

// ---------------- stage 5: selective scan (serial over L) ----------------
__global__ void __launch_bounds__(1024) pex_scan(
    const float* __restrict__ dtw, const float* __restrict__ dtb,
    const float* __restrict__ Alog, const float* __restrict__ Dsp,
    float* __restrict__ ws)
{
    int bid = blockIdx.x;            // ibk*2 + dh
    int dh = bid & 1;
    int ibk = bid >> 1;              // (i*B+b)*4 + k
    int k = ibk & 3;
    int ib = ibk >> 2;
    int i = ib >> 1;
    int tid = threadIdx.x;
    int dl = tid >> 4, n = tid & 15;
    int d = dh * 64 + dl;
    int ks = k & 1;
    bool rev = (k >= 2);
    int pidx = (i * 4 + k) * DI_ + d;
    float A  = -__expf(Alog[(size_t)pidx * 16 + n]);
    float w0 = dtw[(size_t)pidx * 4 + 0];
    float w1 = dtw[(size_t)pidx * 4 + 1];
    float w2 = dtw[(size_t)pidx * 4 + 2];
    float w3 = dtw[(size_t)pidx * 4 + 3];
    float db = dtb[pidx];
    float Dv = Dsp[pidx];
    const float* xbase  = ws + OFF_XS + (size_t)(ib * 2 + ks) * L_ * DI_ + d;
    const float* bcbase = ws + OFF_BC + (size_t)ibk * L_ * 40;
    float* ybase = ws + OFF_YS + (size_t)ibk * L_ * DI_ + d;
    float h = 0.f;
    int tx0 = rev ? (L_ - 1) : 0;
    float x = xbase[(size_t)tx0 * DI_];
    float4 rv = *(const float4*)bcbase;
    float Bv = bcbase[4 + n];
    float Cv = bcbase[20 + n];
    for (int t = 0; t < L_; ++t) {
        float xn = 0.f, Bn2 = 0.f, Cn2 = 0.f;
        float4 rn = rv;
        if (t + 1 < L_) {                         // prefetch next step
            int tx = rev ? (L_ - 2 - t) : (t + 1);
            xn = xbase[(size_t)tx * DI_];
            const float* bp = bcbase + (size_t)(t + 1) * 40;
            rn = *(const float4*)bp;
            Bn2 = bp[4 + n];
            Cn2 = bp[20 + n];
        }
        float dtr = fmaf(rv.x, w0, fmaf(rv.y, w1, fmaf(rv.z, w2, fmaf(rv.w, w3, db))));
        float dt = (dtr > 20.f) ? dtr : log1pf(__expf(dtr));   // softplus
        float dA = __expf(dt * A);
        h = fmaf(dA, h, dt * x * Bv);
        float p = h * Cv;
        p += __shfl_xor(p, 1);
        p += __shfl_xor(p, 2);
        p += __shfl_xor(p, 4);
        p += __shfl_xor(p, 8);
        if (n == 0) ybase[(size_t)t * DI_] = fmaf(Dv, x, p);
        x = xn; rv = rn; Bv = Bn2; Cv = Cn2;
    }
}

// ---------------- stage 6: combine dirs + out-LN + silu(z) gate + out_proj + residual ----------------
__global__ void __launch_bounds__(256) pex_comb(
    const float* __restrict__ og, const float* __restrict__ ob,
    const float* __restrict__ ow, const float* __restrict__ obias,
    float* __restrict__ ws)
{
    int bid = blockIdx.x;
    int i = bid >> 5;
    int r = bid & 31;
    int b = r >> 4;
    int l = (r & 15) * 256 + threadIdx.x;
    int h = l >> 6, w = l & 63;
    int lwh = w * 64 + h;
    int ib = i * B_ + b;
    const float4* y0 = (const float4*)(ws + OFF_YS + ((size_t)(ib * 4 + 0) * L_ + l) * DI_);
    const float4* y1 = (const float4*)(ws + OFF_YS + ((size_t)(ib * 4 + 1) * L_ + lwh) * DI_);
    const float4* y2 = (const float4*)(ws + OFF_YS + ((size_t)(ib * 4 + 2) * L_ + (L_ - 1 - l)) * DI_);
    const float4* y3 = (const float4*)(ws + OFF_YS + ((size_t)(ib * 4 + 3) * L_ + (L_ - 1 - lwh)) * DI_);
    float y[128];
    float s = 0.f;
#pragma unroll
    for (int j = 0; j < 32; ++j) {
        float4 a = y0[j], c = y1[j], e = y2[j], g = y3[j];
        float v0 = a.x + c.x + e.x + g.x;
        float v1 = a.y + c.y + e.y + g.y;
        float v2 = a.z + c.z + e.z + g.z;
        float v3 = a.w + c.w + e.w + g.w;
        y[j*4+0] = v0; y[j*4+1] = v1; y[j*4+2] = v2; y[j*4+3] = v3;
        s += (v0 + v1) + (v2 + v3);
    }
    float mean = s * (1.f / 128.f);
    float vs = 0.f;
#pragma unroll
    for (int dd = 0; dd < 128; ++dd) { float t = y[dd] - mean; vs = fmaf(t, t, vs); }
    float rs = rsqrtf(vs * (1.f / 128.f) + 1e-5f);
    const float* zp = ws + OFF_Z + (size_t)ib * DI_ * L_ + l;
#pragma unroll
    for (int dd = 0; dd < 128; ++dd) {
        float zv = zp[(size_t)dd * L_];
        float sil = zv / (1.f + __expf(-zv));
        y[dd] = ((y[dd] - mean) * rs * og[i * 128 + dd] + ob[i * 128 + dd]) * sil;
    }
    int src = (i + h % 3 + w % 3) % 3;
    const float* fe = ws + OFF_FE + (size_t)(src * B_ + b) * 64 * L_ + l;
    float* vo = ws + OFF_VSS + (size_t)ib * 64 * L_ + l;
    const float* wb = ow + (size_t)i * 64 * DI_;
    for (int c = 0; c < 64; ++c) {
        const float4* wr = (const float4*)(wb + c * DI_);
        float acc = obias[i * 64 + c];
#pragma unroll
        for (int j = 0; j < 32; ++j) {
            float4 wv = wr[j];
            acc = fmaf(y[j*4+0], wv.x, acc);
            acc = fmaf(y[j*4+1], wv.y, acc);
            acc = fmaf(y[j*4+2], wv.z, acc);
            acc = fmaf(y[j*4+3], wv.w, acc);
        }
        vo[(size_t)c * L_] = fe[(size_t)c * L_] + acc;
    }
}

// ---------------- stage 7: Q/V from v3, K1 from v1, K2 from v2 ----------------
__global__ void __launch_bounds__(256) pex_qkv(
    const float* __restrict__ qw, const float* __restrict__ qb,
    const float* __restrict__ vw, const float* __restrict__ vb,
    const float* __restrict__ k1w, const float* __restrict__ k1b,
    const float* __restrict__ k2w, const float* __restrict__ k2b,
    float* __restrict__ ws)
{
    int which = blockIdx.y;
    int bid = blockIdx.x;
    int b = bid >> 4;
    int l = (bid & 15) * 256 + threadIdx.x;
    int isrc = (which == 0) ? 2 : (which - 1);
    const float* vp = ws + OFF_VSS + (size_t)(isrc * B_ + b) * 64 * L_ + l;
    float f[64];
#pragma unroll
    for (int c = 0; c < 64; ++c) f[c] = vp[(size_t)c * L_];
    if (which == 0) {
        float* Qp = ws + OFF_Q + ((size_t)b * L_ + l) * 64;
        float* Vp = ws + OFF_V + ((size_t)b * L_ + l) * 64;
        for (int c = 0; c < 64; ++c) {
            const float4* wr = (const float4*)(qw + c * 64);
            float acc = qb[c];
#pragma unroll
            for (int j = 0; j < 16; ++j) {
                float4 w = wr[j];
                acc = fmaf(f[j*4+0], w.x, acc);
                acc = fmaf(f[j*4+1], w.y, acc);
                acc = fmaf(f[j*4+2], w.z, acc);
                acc = fmaf(f[j*4+3], w.w, acc);
            }
            Qp[c] = acc;
        }
        for (int c = 0; c < 64; ++c) {
            const float4* wr = (const float4*)(vw + c * 64);
            float acc = vb[c];
#pragma unroll
            for (int j = 0; j < 16; ++j) {
                float4 w = wr[j];
                acc = fmaf(f[j*4+0], w.x, acc);
                acc = fmaf(f[j*4+1], w.y, acc);
                acc = fmaf(f[j*4+2], w.z, acc);
                acc = fmaf(f[j*4+3], w.w, acc);
            }
            Vp[c] = acc;
        }
    } else {
        const float* kw = (which == 1) ? k1w : k2w;
        const float* kb = (which == 1) ? k1b : k2b;
        float* Kp = ws + ((which == 1) ? OFF_K1 : OFF_K2) + (size_t)b * 64 * L_ + l;
        for (int c = 0; c < 64; ++c) {
            const float4* wr = (const float4*)(kw + c * 64);
            float acc = kb[c];
#pragma unroll
            for (int j = 0; j < 16; ++j) {
                float4 w = wr[j];
                acc = fmaf(f[j*4+0], w.x, acc);
                acc = fmaf(f[j*4+1], w.y, acc);
                acc = fmaf(f[j*4+2], w.z, acc);
                acc = fmaf(f[j*4+3], w.w, acc);
            }
            Kp[(size_t)c * L_] = acc;
        }
    }
}

// ---------------- stage 8: flash-style attention, one (b, map, 64q-tile) per block ----------------
__global__ void __launch_bounds__(256) pex_attn(float* __restrict__ ws)
{
    __shared__ float Qs[64 * 68];
    __shared__ float Ks[64 * 68];   // reused as P tile
    __shared__ float Vs[64 * 68];
    int bid = blockIdx.x;
    int qt = bid & 63;
    int m  = (bid >> 6) & 1;
    int b  = bid >> 7;
    const float* Qg = ws + OFF_Q + ((size_t)b * L_ + qt * 64) * 64;
    const float* Kg = ws + (m ? OFF_K2 : OFF_K1) + (size_t)b * 64 * L_;
    const float* Vg = ws + OFF_V + (size_t)b * L_ * 64;
    float* Og = ws + (m ? OFF_O2 : OFF_O1) + ((size_t)b * L_ + qt * 64) * 64;
    int tid = threadIdx.x;
    int qb = tid >> 4, mb = tid & 15;
    int q0 = qb * 4, c0 = mb * 4;
#pragma unroll
    for (int j = 0; j < 4; ++j) {
        int e = j * 1024 + tid * 4;
        int row = e >> 6, col = e & 63;
        float4 qv = *(const float4*)&Qg[row * 64 + col];
        qv.x *= 0.125f; qv.y *= 0.125f; qv.z *= 0.125f; qv.w *= 0.125f;
        *(float4*)&Qs[row * 68 + col] = qv;
    }
    float acc[4][4];
    float mrun[4], lrun[4];
#pragma unroll
    for (int ii = 0; ii < 4; ++ii) {
        mrun[ii] = -INFINITY; lrun[ii] = 0.f;
#pragma unroll
        for (int jj = 0; jj < 4; ++jj) acc[ii][jj] = 0.f;
    }
    for (int kt = 0; kt < 64; ++kt) {
        int ko = kt * 64;
        __syncthreads();             // prior PV done before overwriting Ks/Vs
#pragma unroll
        for (int j = 0; j < 4; ++j) {
            int e = j * 1024 + tid * 4;
            int row = e >> 6, col = e & 63;
            *(float4*)&Ks[row * 68 + col] = *(const float4*)&Kg[(size_t)row * L_ + ko + col];
            *(float4*)&Vs[row * 68 + col] = *(const float4*)&Vg[(size_t)(ko + row) * 64 + col];
        }
        __syncthreads();
        float s[4][4];
#pragma unroll
        for (int ii = 0; ii < 4; ++ii)
#pragma unroll
            for (int jj = 0; jj < 4; ++jj) s[ii][jj] = 0.f;
        for (int c = 0; c < 64; ++c) {
            float4 kv = *(const float4*)&Ks[c * 68 + c0];
            float a0 = Qs[(q0 + 0) * 68 + c];
            float a1 = Qs[(q0 + 1) * 68 + c];
            float a2 = Qs[(q0 + 2) * 68 + c];
            float a3 = Qs[(q0 + 3) * 68 + c];
            s[0][0] = fmaf(a0, kv.x, s[0][0]); s[0][1] = fmaf(a0, kv.y, s[0][1]);
            s[0][2] = fmaf(a0, kv.z, s[0][2]); s[0][3] = fmaf(a0, kv.w, s[0][3]);
            s[1][0] = fmaf(a1, kv.x, s[1][0]); s[1][1] = fmaf(a1, kv.y, s[1][1]);
            s[1][2] = fmaf(a1, kv.z, s[1][2]); s[1][3] = fmaf(a1, kv.w, s[1][3]);
            s[2][0] = fmaf(a2, kv.x, s[2][0]); s[2][1] = fmaf(a2, kv.y, s[2][1]);
            s[2][2] = fmaf(a2, kv.z, s[2][2]); s[2][3] = fmaf(a2, kv.w, s[2][3]);
            s[3][0] = fmaf(a3, kv.x, s[3][0]); s[3][1] = fmaf(a3, kv.y, s[3][1]);
            s[3][2] = fmaf(a3, kv.z, s[3][2]); s[3][3] = fmaf(a3, kv.w, s[3][3]);
        }
        __syncthreads();             // all S reads of Ks done before P overwrite
        float pv[4][4];
#pragma unroll
        for (int ii = 0; ii < 4; ++ii) {
            float tm = fmaxf(fmaxf(s[ii][0], s[ii][1]), fmaxf(s[ii][2], s[ii][3]));
            tm = fmaxf(tm, __shfl_xor(tm, 1));
            tm = fmaxf(tm, __shfl_xor(tm, 2));
            tm = fmaxf(tm, __shfl_xor(tm, 4));
            tm = fmaxf(tm, __shfl_xor(tm, 8));
            float mn = fmaxf(mrun[ii], tm);
            float co = __expf(mrun[ii] - mn);
            float ts = 0.f;
#pragma unroll
            for (int jj = 0; jj < 4; ++jj) {
                float e2 = __expf(s[ii][jj] - mn);
                pv[ii][jj] = e2;
                ts += e2;
            }
            ts += __shfl_xor(ts, 1);
            ts += __shfl_xor(ts, 2);
            ts += __shfl_xor(ts, 4);
            ts += __shfl_xor(ts, 8);
            lrun[ii] = lrun[ii] * co + ts;
            mrun[ii] = mn;
#pragma unroll
            for (int jj = 0; jj < 4; ++jj) acc[ii][jj] *= co;
        }
#pragma unroll
        for (int ii = 0; ii < 4; ++ii)
            *(float4*)&Ks[(q0 + ii) * 68 + c0] =
                make_float4(pv[ii][0], pv[ii][1], pv[ii][2], pv[ii][3]);
        __syncthreads();
        for (int mm = 0; mm < 64; ++mm) {
            float4 vv = *(const float4*)&Vs[mm * 68 + c0];
            float p0 = Ks[(q0 + 0) * 68 + mm];
            float p1 = Ks[(q0 + 1) * 68 + mm];
            float p2 = Ks[(q0 + 2) * 68 + mm];
            float p3 = Ks[(q0 + 3) * 68 + mm];
            acc[0][0] = fmaf(p0, vv.x, acc[0][0]); acc[0][1] = fmaf(p0, vv.y, acc[0][1]);
            acc[0][2] = fmaf(p0, vv.z, acc[0][2]); acc[0][3] = fmaf(p0, vv.w, acc[0][3]);
            acc[1][0] = fmaf(p1, vv.x, acc[1][0]); acc[1][1] = fmaf(p1, vv.y, acc[1][1]);
            acc[1][2] = fmaf(p1, vv.z, acc[1][2]); acc[1][3] = fmaf(p1, vv.w, acc[1][3]);
            acc[2][0] = fmaf(p2, vv.x, acc[2][0]); acc[2][1] = fmaf(p2, vv.y, acc[2][1]);
            acc[2][2] = fmaf(p2, vv.z, acc[2][2]); acc[2][3] = fmaf(p2, vv.w, acc[2][3]);
            acc[3][0] = fmaf(p3, vv.x, acc[3][0]); acc[3][1] = fmaf(p3, vv.y, acc[3][1]);
            acc[3][2] = fmaf(p3, vv.z, acc[3][2]); acc[3][3] = fmaf(p3, vv.w, acc[3][3]);
        }
    }
#pragma unroll
    for (int ii = 0; ii < 4; ++ii) {
        float inv = 1.f / lrun[ii];
        *(float4*)&Og[(size_t)(q0 + ii) * 64 + c0] =
            make_float4(acc[ii][0] * inv, acc[ii][1] * inv, acc[ii][2] * inv, acc[ii][3] * inv);
    }
}

// ---------------- stage 9: proj over cat([O1+O2, v1, v2]) ----------------
__global__ void __launch_bounds__(256) pex_proj(
    const float* __restrict__ pbias, float* __restrict__ ws)
{
    int bid = blockIdx.x;
    int b = bid >> 4;
    int l = (bid & 15) * 256 + threadIdx.x;
    float acc[64];
#pragma unroll
    for (int c = 0; c < 64; ++c) acc[c] = pbias[c];
    const float* pwT = ws + OFF_PWT;
    const float4* o1 = (const float4*)(ws + OFF_O1 + ((size_t)b * L_ + l) * 64);
    const float4* o2 = (const float4*)(ws + OFF_O2 + ((size_t)b * L_ + l) * 64);
#pragma unroll
    for (int j = 0; j < 16; ++j) {
        float4 a = o1[j], d = o2[j];
        float v[4] = {a.x + d.x, a.y + d.y, a.z + d.z, a.w + d.w};
#pragma unroll
        for (int jj = 0; jj < 4; ++jj) {
            const float4* wr = (const float4*)(pwT + (j * 4 + jj) * 64);
#pragma unroll
            for (int u = 0; u < 16; ++u) {
                float4 w = wr[u];
                acc[u*4+0] = fmaf(v[jj], w.x, acc[u*4+0]);
                acc[u*4+1] = fmaf(v[jj], w.y, acc[u*4+1]);
                acc[u*4+2] = fmaf(v[jj], w.z, acc[u*4+2]);
                acc[u*4+3] = fmaf(v[jj], w.w, acc[u*4+3]);
            }
        }
    }
    for (int part = 0; part < 2; ++part) {
        const float* vp = ws + OFF_VSS + (size_t)(part * B_ + b) * 64 * L_ + l;
        for (int cc = 0; cc < 64; ++cc) {
            float v = vp[(size_t)cc * L_];
            const float4* wr = (const float4*)(pwT + (64 + part * 64 + cc) * 64);
#pragma unroll
            for (int u = 0; u < 16; ++u) {
                float4 w = wr[u];
                acc[u*4+0] = fmaf(v, w.x, acc[u*4+0]);
                acc[u*4+1] = fmaf(v, w.y, acc[u*4+1]);
                acc[u*4+2] = fmaf(v, w.z, acc[u*4+2]);
                acc[u*4+3] = fmaf(v, w.w, acc[u*4+3]);
            }
        }
    }
    float* rp = ws + OFF_RAW + (size_t)b * 64 * L_ + l;
#pragma unroll
    for (int c = 0; c < 64; ++c) rp[(size_t)c * L_] = acc[c];
}

// ---------------- stage 9b: per-channel BN stats ----------------
__global__ void __launch_bounds__(256) pex_stats(float* __restrict__ ws)
{
    int c = blockIdx.x;
    float s = 0.f, s2 = 0.f;
    for (int idx = threadIdx.x; idx < B_ * L_; idx += 256) {
        int b = idx >> 12;
        int l = idx & 4095;
        float v = ws[OFF_RAW + (size_t)(b * 64 + c) * L_ + l];
        s += v;
        s2 = fmaf(v, v, s2);
    }
    for (int off = 1; off < 64; off <<= 1) {
        s  += __shfl_xor(s, off);
        s2 += __shfl_xor(s2, off);
    }
    __shared__ float ps[8];
    int wid = threadIdx.x >> 6;
    if ((threadIdx.x & 63) == 0) { ps[wid] = s; ps[4 + wid] = s2; }
    __syncthreads();
    if (threadIdx.x == 0) {
        ws[OFF_ST + c]      = ps[0] + ps[1] + ps[2] + ps[3];
        ws[OFF_ST + 64 + c] = ps[4] + ps[5] + ps[6] + ps[7];
    }
}

// ---------------- stage 10: BN + ReLU ----------------
__global__ void __launch_bounds__(256) pex_bn(
    const float* __restrict__ bng, const float* __restrict__ bnb,
    float* __restrict__ out, const float* __restrict__ ws)
{
    int idx = blockIdx.x * 256 + threadIdx.x;     // (b*64+c)*4096 + l
    int c = (idx >> 12) & 63;
    float sum  = ws[OFF_ST + c];
    float sum2 = ws[OFF_ST + 64 + c];
    float mean = sum * (1.f / 8192.f);
    float var  = sum2 * (1.f / 8192.f) - mean * mean;
    float x = ws[OFF_RAW + idx];
    float y = (x - mean) * rsqrtf(var + 1e-5f) * bng[c] + bnb[c];
    out[idx] = fmaxf(y, 0.f);
}

extern "C" void kernel_launch(void* const* d_in, const int* in_sizes, int n_in,
                              void* d_out, int out_size, void* d_ws, size_t ws_size,
                              hipStream_t stream)
{
    (void)in_sizes; (void)n_in; (void)out_size; (void)ws_size;
    float* ws = (float*)d_ws;
    const float* x1      = (const float*)d_in[0];
    const float* x2      = (const float*)d_in[1];
    const float* x3      = (const float*)d_in[2];
    const float* aw1     = (const float*)d_in[3];
    const float* ab1     = (const float*)d_in[4];
    const float* aw2     = (const float*)d_in[5];
    const float* ab2     = (const float*)d_in[6];
    const float* aw3     = (const float*)d_in[7];
    const float* ab3     = (const float*)d_in[8];
    const float* ln_g    = (const float*)d_in[9];
    const float* ln_b    = (const float*)d_in[10];
    const float* in_w    = (const float*)d_in[11];
    const float* in_b    = (const float*)d_in[12];
    const float* conv_w  = (const float*)d_in[13];
    const float* conv_b  = (const float*)d_in[14];
    const float* xproj_w = (const float*)d_in[15];
    const float* dt_w    = (const float*)d_in[16];
    const float* dt_b    = (const float*)d_in[17];
    const float* A_log   = (const float*)d_in[18];
    const float* Ds      = (const float*)d_in[19];
    const float* onorm_g = (const float*)d_in[20];
    const float* onorm_b = (const float*)d_in[21];
    const float* out_w   = (const float*)d_in[22];
    const float* out_b   = (const float*)d_in[23];
    const float* k1_w    = (const float*)d_in[24];
    const float* k1_b    = (const float*)d_in[25];
    const float* k2_w    = (const float*)d_in[26];
    const float* k2_b    = (const float*)d_in[27];
    const float* q3_w    = (const float*)d_in[28];
    const float* q3_b    = (const float*)d_in[29];
    const float* v3_w    = (const float*)d_in[30];
    const float* v3_b    = (const float*)d_in[31];
    const float* proj_w  = (const float*)d_in[32];
    const float* proj_b  = (const float*)d_in[33];
    const float* bn_g    = (const float*)d_in[34];
    const float* bn_b    = (const float*)d_in[35];

    pex_prep  <<<128, 256, 0, stream>>>(aw1, aw2, aw3, proj_w, ws);
    pex_feats <<<dim3(96, 2), 256, 0, stream>>>(x1, x2, x3, ab1, ab2, ab3, ws);
    pex_lnproj<<<dim3(96, 2), 256, 0, stream>>>(ln_g, ln_b, in_w, in_b, ws);
    pex_conv  <<<768, 256, 0, stream>>>(conv_w, conv_b, ws);
    pex_xst   <<<1536, 256, 0, stream>>>(ws);
    pex_bct   <<<384, 256, 0, stream>>>(xproj_w, ws);
    pex_scan  <<<48, 1024, 0, stream>>>(dt_w, dt_b, A_log, Ds, ws);
    pex_comb  <<<96, 256, 0, stream>>>(onorm_g, onorm_b, out_w, out_b, ws);
    pex_qkv   <<<dim3(32, 3), 256, 0, stream>>>(q3_w, q3_b, v3_w, v3_b, k1_w, k1_b, k2_w, k2_b, ws);
    pex_attn  <<<256, 256, 0, stream>>>(ws);
    pex_proj  <<<32, 256, 0, stream>>>(proj_b, ws);
    pex_stats <<<64, 256, 0, stream>>>(ws);
    pex_bn    <<<2048, 256, 0, stream>>>(bn_g, bn_b, (float*)d_out, ws);
}

// Round 2
// 1533.086 us; speedup vs baseline: 3.4023x; 3.4023x over previous
//
#include <hip/hip_runtime.h>
#include <math.h>

// Problem constants
#define B_   2
#define L_   4096
#define DI_  128
#define NCHUNK 32
#define TCHUNK 128   // L_/NCHUNK

// -------- workspace layout (float offsets), stage-lifetime aliased --------
// [0, 3.15M):    XC (lnproj->conv)  then Y accumulator (scan3->comb, memset after bct)
static constexpr size_t OFF_XC   = 0;           // 3,145,728
static constexpr size_t OFF_Y    = 0;           // 3,145,728
static constexpr size_t OFF_XC2  = 3145728;     // 3,145,728 (conv->scan3); VSS aliases after
static constexpr size_t OFF_XC2T = 6291456;     // 3,145,728 (conv->scan3); QKV/O alias after
static constexpr size_t OFF_BC   = 9437184;     // 24*4096*36 = 3,538,944 (bct->scan3); RAW aliases after
static constexpr size_t OFF_SCA  = 12976128;    // 48*32*1024 = 1,572,864 (scan1->scan3, becomes hstart)
static constexpr size_t OFF_SCB  = 14548992;    // 1,572,864 (scan1->scan2)
static constexpr size_t OFF_FE   = 16121856;    // 1,572,864 (feats->comb)
static constexpr size_t OFF_Z    = 17694720;    // 3,145,728 (lnproj->comb)
static constexpr size_t OFF_AWT1 = 20840448;    // 8192
static constexpr size_t OFF_AWT2 = 20848640;    // 16384
static constexpr size_t OFF_AWT3 = 20865024;    // 32768
static constexpr size_t OFF_PWT  = 20897792;    // 12288  -> total 20,910,080 floats = 83.6 MB
// post-scan aliases:
static constexpr size_t OFF_VSS  = 3145728;     // over XC2  (comb->proj), 1,572,864
static constexpr size_t OFF_Q    = 6291456;     // over XC2T
static constexpr size_t OFF_K1   = 6815744;
static constexpr size_t OFF_K2   = 7340032;
static constexpr size_t OFF_V    = 7864320;
static constexpr size_t OFF_O1   = 8388608;
static constexpr size_t OFF_O2   = 8912896;     // ends exactly at OFF_BC
static constexpr size_t OFF_RAW  = 9437184;     // over BC (proj->bn), 524,288
static constexpr size_t OFF_ST   = 9961472;

// ---------------- weight transposes ----------------
__global__ void __launch_bounds__(256) pex_prep(
    const float* __restrict__ aw1, const float* __restrict__ aw2,
    const float* __restrict__ aw3, const float* __restrict__ pw,
    float* __restrict__ ws)
{
    int idx = blockIdx.x * 256 + threadIdx.x;   // 32768 total
    int ic = idx >> 6, c = idx & 63;
    if (ic < 128) ws[OFF_AWT1 + idx] = aw1[c * 128 + ic];
    if (ic < 256) ws[OFF_AWT2 + idx] = aw2[c * 256 + ic];
    ws[OFF_AWT3 + idx] = aw3[c * 512 + ic];
    if (idx < 192 * 64) {
        int cp = idx >> 6;
        ws[OFF_PWT + idx] = pw[c * 192 + cp];
    }
}

// ---------------- stage 1: feats = conv1x1(x_i) ----------------
__global__ void __launch_bounds__(256) pex_feats(
    const float* __restrict__ x1, const float* __restrict__ x2, const float* __restrict__ x3,
    const float* __restrict__ ab1, const float* __restrict__ ab2, const float* __restrict__ ab3,
    float* __restrict__ ws)
{
    int bid = blockIdx.x;            // i*32 + b*16 + pt
    int i = bid >> 5;
    int r = bid & 31;
    int b = r >> 4;
    int p = (r & 15) * 256 + threadIdx.x;
    int c0 = blockIdx.y * 32;
    const float* xp; const float* ab; const float* awT; int IC;
    if (i == 0)      { xp = x1; ab = ab1; awT = ws + OFF_AWT1; IC = 128; }
    else if (i == 1) { xp = x2; ab = ab2; awT = ws + OFF_AWT2; IC = 256; }
    else             { xp = x3; ab = ab3; awT = ws + OFF_AWT3; IC = 512; }
    xp += (size_t)b * IC * L_ + p;
    float acc[32];
#pragma unroll
    for (int c = 0; c < 32; ++c) acc[c] = ab[c0 + c];
    for (int ic = 0; ic < IC; ++ic) {
        float v = xp[(size_t)ic * L_];
        const float4* wr = (const float4*)(awT + ic * 64 + c0);
#pragma unroll
        for (int j = 0; j < 8; ++j) {
            float4 w = wr[j];
            acc[j*4+0] = fmaf(v, w.x, acc[j*4+0]);
            acc[j*4+1] = fmaf(v, w.y, acc[j*4+1]);
            acc[j*4+2] = fmaf(v, w.z, acc[j*4+2]);
            acc[j*4+3] = fmaf(v, w.w, acc[j*4+3]);
        }
    }
    float* fe = ws + OFF_FE + ((size_t)(i * B_ + b) * 64 + c0) * L_ + p;
#pragma unroll
    for (int c = 0; c < 32; ++c) fe[(size_t)c * L_] = acc[c];
}

// ---------------- stage 2: pixel-exchange gather + LN + in_proj ----------------
__global__ void __launch_bounds__(256) pex_lnproj(
    const float* __restrict__ lng, const float* __restrict__ lnb,
    const float* __restrict__ inw, const float* __restrict__ inb,
    float* __restrict__ ws)
{
    int bid = blockIdx.x;
    int i = bid >> 5;
    int r = bid & 31;
    int b = r >> 4;
    int p = (r & 15) * 256 + threadIdx.x;
    int h = p >> 6, w = p & 63;
    int src = (i + h % 3 + w % 3) % 3;
    const float* fe = ws + OFF_FE + (size_t)(src * B_ + b) * 64 * L_ + p;
    float f[64];
    float s = 0.f;
#pragma unroll
    for (int c = 0; c < 64; ++c) { f[c] = fe[(size_t)c * L_]; s += f[c]; }
    float mean = s * (1.f / 64.f);
    float vs = 0.f;
#pragma unroll
    for (int c = 0; c < 64; ++c) { float d = f[c] - mean; vs = fmaf(d, d, vs); }
    float rs = rsqrtf(vs * (1.f / 64.f) + 1e-5f);
#pragma unroll
    for (int c = 0; c < 64; ++c)
        f[c] = (f[c] - mean) * rs * lng[i * 64 + c] + lnb[i * 64 + c];

    const float* wbase = inw + (size_t)i * 256 * 64;
    float* outp = (blockIdx.y == 0)
        ? (ws + OFF_XC + (size_t)(i * B_ + b) * DI_ * L_ + p)
        : (ws + OFF_Z  + (size_t)(i * B_ + b) * DI_ * L_ + p);
    int oc0 = blockIdx.y * 128;
    for (int oc = 0; oc < 128; ++oc) {
        int oca = oc0 + oc;
        const float4* wr = (const float4*)(wbase + oca * 64);
        float acc = inb[i * 256 + oca];
#pragma unroll
        for (int j = 0; j < 16; ++j) {
            float4 w = wr[j];
            acc = fmaf(f[j*4+0], w.x, acc);
            acc = fmaf(f[j*4+1], w.y, acc);
            acc = fmaf(f[j*4+2], w.z, acc);
            acc = fmaf(f[j*4+3], w.w, acc);
        }
        outp[(size_t)oc * L_] = acc;
    }
}

// ---------------- stage 3: depthwise 3x3 conv + SiLU, write HW and WH layouts ----------------
__global__ void __launch_bounds__(256) pex_conv(
    const float* __restrict__ cw, const float* __restrict__ cb, float* __restrict__ ws)
{
    __shared__ float sm[64 * 65];
    int bid = blockIdx.x;          // i*256 + b*128 + d
    int i = bid >> 8;
    int r = bid & 255;
    int b = r >> 7;
    int d = r & 127;
    float wk[9];
#pragma unroll
    for (int j = 0; j < 9; ++j) wk[j] = cw[(size_t)(i * DI_ + d) * 9 + j];
    float bias = cb[i * DI_ + d];
    const float* xin = ws + OFF_XC + ((size_t)(i * B_ + b) * DI_ + d) * L_;
    float* xo  = ws + OFF_XC2  + ((size_t)(i * B_ + b) * DI_ + d) * L_;
    float* xoT = ws + OFF_XC2T + ((size_t)(i * B_ + b) * DI_ + d) * L_;
#pragma unroll
    for (int j = 0; j < 16; ++j) {
        int p = j * 256 + threadIdx.x;
        int h = p >> 6, w = p & 63;
        float acc = bias;
#pragma unroll
        for (int dh = 0; dh < 3; ++dh) {
            int hh = h + dh - 1;
            if (hh < 0 || hh > 63) continue;
#pragma unroll
            for (int dw = 0; dw < 3; ++dw) {
                int ww = w + dw - 1;
                if (ww < 0 || ww > 63) continue;
                acc = fmaf(xin[hh * 64 + ww], wk[dh * 3 + dw], acc);
            }
        }
        float v = acc / (1.f + __expf(-acc));
        xo[p] = v;
        sm[h * 65 + w] = v;
    }
    __syncthreads();
#pragma unroll
    for (int j = 0; j < 16; ++j) {
        int q = j * 256 + threadIdx.x;
        int h = q & 63, w = q >> 6;       // q = w*64 + h
        xoT[q] = sm[h * 65 + w];
    }
}

// ---------------- stage 4: x_dbl -> bc_t (r[4], B[16], C[16]) ----------------
__global__ void __launch_bounds__(256) pex_bct(
    const float* __restrict__ xpw, float* __restrict__ ws)
{
    int bid = blockIdx.x;            // ibk*16 + tt
    int tt = bid & 15;
    int ibk = bid >> 4;              // (i*B+b)*4 + k
    int k = ibk & 3;
    int ib = ibk >> 2;
    int i = ib >> 1;
    int t = tt * 256 + threadIdx.x;
    int ks = k & 1;
    int tx = (k >= 2) ? (L_ - 1 - t) : t;
    const float* xb = ws + (ks ? OFF_XC2T : OFF_XC2) + (size_t)ib * DI_ * L_ + tx;
    float xv[DI_];
#pragma unroll
    for (int dd = 0; dd < DI_; ++dd) xv[dd] = xb[(size_t)dd * L_];
    float* out = ws + OFF_BC + ((size_t)ibk * L_ + t) * 36;
    const float* wb = xpw + (size_t)(i * 4 + k) * 36 * DI_;
    for (int c = 0; c < 36; ++c) {
        const float4* wr = (const float4*)(wb + c * DI_);
        float acc = 0.f;
#pragma unroll
        for (int j = 0; j < 32; ++j) {
            float4 w = wr[j];
            acc = fmaf(xv[4*j+0], w.x, acc);
            acc = fmaf(xv[4*j+1], w.y, acc);
            acc = fmaf(xv[4*j+2], w.z, acc);
            acc = fmaf(xv[4*j+3], w.w, acc);
        }
        out[c] = acc;
    }
}

// ---------------- stage 5a: per-chunk (A_prod, B_local) ----------------
__global__ void __launch_bounds__(1024) pex_scan1(
    const float* __restrict__ dtw, const float* __restrict__ dtb,
    const float* __restrict__ Alog, float* __restrict__ ws)
{
    int grp = blockIdx.x;            // ibk*2 + dh
    int chunk = blockIdx.y;
    int dh = grp & 1;
    int ibk = grp >> 1;
    int k = ibk & 3;
    int ib = ibk >> 2;
    int i = ib >> 1;
    int tid = threadIdx.x;
    int dl = tid >> 4, n = tid & 15;
    int d = dh * 64 + dl;
    int ks = k & 1;
    bool rev = (k >= 2);
    int pidx = (i * 4 + k) * DI_ + d;
    float A  = -__expf(Alog[(size_t)pidx * 16 + n]);
    float w0 = dtw[(size_t)pidx * 4 + 0];
    float w1 = dtw[(size_t)pidx * 4 + 1];
    float w2 = dtw[(size_t)pidx * 4 + 2];
    float w3 = dtw[(size_t)pidx * 4 + 3];
    float db = dtb[pidx];
    const float* xb  = ws + (ks ? OFF_XC2T : OFF_XC2) + ((size_t)ib * DI_ + d) * L_;
    const float* bcb = ws + OFF_BC + (size_t)ibk * L_ * 36;
    float h = 0.f, ap = 1.f;
    int t0 = chunk * TCHUNK;
#pragma unroll 4
    for (int tt = 0; tt < TCHUNK; ++tt) {
        int t = t0 + tt;
        int tx = rev ? (L_ - 1 - t) : t;
        const float* bp = bcb + (size_t)t * 36;
        float4 rv = *(const float4*)bp;
        float Bv = bp[4 + n];
        float x = xb[tx];
        float dtr = fmaf(rv.x, w0, fmaf(rv.y, w1, fmaf(rv.z, w2, fmaf(rv.w, w3, db))));
        float dt = (dtr > 20.f) ? dtr : __logf(1.f + __expf(dtr));
        float dA = __expf(dt * A);
        h = fmaf(dA, h, dt * x * Bv);
        ap *= dA;
    }
    size_t o = ((size_t)grp * NCHUNK + chunk) * 1024 + tid;
    ws[OFF_SCA + o] = ap;
    ws[OFF_SCB + o] = h;
}

// ---------------- stage 5b: compose chunk prefixes (hstart into SCA) ----------------
__global__ void __launch_bounds__(256) pex_scan2(float* __restrict__ ws)
{
    int chain = blockIdx.x * 256 + threadIdx.x;   // 49152 chains
    int grp = chain >> 10;
    int lane = chain & 1023;
    float h = 0.f;
    for (int c = 0; c < NCHUNK; ++c) {
        size_t o = ((size_t)grp * NCHUNK + c) * 1024 + lane;
        float a = ws[OFF_SCA + o];
        float b = ws[OFF_SCB + o];
        ws[OFF_SCA + o] = h;       // state at chunk start
        h = fmaf(a, h, b);
    }
}

// ---------------- stage 5c: re-run chunks with true h0, emit y into combined Y ----------------
__global__ void __launch_bounds__(1024) pex_scan3(
    const float* __restrict__ dtw, const float* __restrict__ dtb,
    const float* __restrict__ Alog, const float* __restrict__ Dsp,
    float* __restrict__ ws)
{
    int grp = blockIdx.x;
    int chunk = blockIdx.y;
    int dh = grp & 1;
    int ibk = grp >> 1;
    int k = ibk & 3;
    int ib = ibk >> 2;
    int i = ib >> 1;
    int tid = threadIdx.x;
    int dl = tid >> 4, n = tid & 15;
    int d = dh * 64 + dl;
    int ks = k & 1;
    bool rev = (k >= 2);
    int pidx = (i * 4 + k) * DI_ + d;
    float A  = -__expf(Alog[(size_t)pidx * 16 + n]);
    float w0 = dtw[(size_t)pidx * 4 + 0];
    float w1 = dtw[(size_t)pidx * 4 + 1];
    float w2 = dtw[(size_t)pidx * 4 + 2];
    float w3 = dtw[(size_t)pidx * 4 + 3];
    float db = dtb[pidx];
    float Dv = Dsp[pidx];
    const float* xb  = ws + (ks ? OFF_XC2T : OFF_XC2) + ((size_t)ib * DI_ + d) * L_;
    const float* bcb = ws + OFF_BC + (size_t)ibk * L_ * 36;
    float* yb = ws + OFF_Y + (size_t)ib * L_ * DI_ + d;
    float h = ws[OFF_SCA + ((size_t)grp * NCHUNK + chunk) * 1024 + tid];
    int t0 = chunk * TCHUNK;
#pragma unroll 2
    for (int tt = 0; tt < TCHUNK; ++tt) {
        int t = t0 + tt;
        int tx = rev ? (L_ - 1 - t) : t;
        const float* bp = bcb + (size_t)t * 36;
        float4 rv = *(const float4*)bp;
        float Bv = bp[4 + n];
        float Cv = bp[20 + n];
        float x = xb[tx];
        float dtr = fmaf(rv.x, w0, fmaf(rv.y, w1, fmaf(rv.z, w2, fmaf(rv.w, w3, db))));
        float dt = (dtr > 20.f) ? dtr : __logf(1.f + __expf(dtr));
        float dA = __expf(dt * A);
        h = fmaf(dA, h, dt * x * Bv);
        float p = h * Cv;
        p += __shfl_xor(p, 1);
        p += __shfl_xor(p, 2);
        p += __shfl_xor(p, 4);
        p += __shfl_xor(p, 8);
        if (n == 0) {
            // contribution position: u = tx in layout order; ks=1 layouts are wh-order
            int u = tx;
            int l = ks ? ((u & 63) * 64 + (u >> 6)) : u;
            atomicAdd(&yb[(size_t)l * DI_], fmaf(Dv, x, p));
        }
    }
}

// ---------------- stage 6: out-LN + silu(z) gate + out_proj + residual ----------------
__global__ void __launch_bounds__(256) pex_comb(
    const float* __restrict__ og, const float* __restrict__ ob,
    const float* __restrict__ ow, const float* __restrict__ obias,
    float* __restrict__ ws)
{
    int bid = blockIdx.x;
    int i = bid >> 5;
    int r = bid & 31;
    int b = r >> 4;
    int l = (r & 15) * 256 + threadIdx.x;
    int h = l >> 6, w = l & 63;
    int ib = i * B_ + b;
    const float4* yp = (const float4*)(ws + OFF_Y + ((size_t)ib * L_ + l) * DI_);
    float y[128];
    float s = 0.f;
#pragma unroll
    for (int j = 0; j < 32; ++j) {
        float4 a = yp[j];
        y[j*4+0] = a.x; y[j*4+1] = a.y; y[j*4+2] = a.z; y[j*4+3] = a.w;
        s += (a.x + a.y) + (a.z + a.w);
    }
    float mean = s * (1.f / 128.f);
    float vs = 0.f;
#pragma unroll
    for (int dd = 0; dd < 128; ++dd) { float t = y[dd] - mean; vs = fmaf(t, t, vs); }
    float rs = rsqrtf(vs * (1.f / 128.f) + 1e-5f);
    const float* zp = ws + OFF_Z + (size_t)ib * DI_ * L_ + l;
#pragma unroll
    for (int dd = 0; dd < 128; ++dd) {
        float zv = zp[(size_t)dd * L_];
        float sil = zv / (1.f + __expf(-zv));
        y[dd] = ((y[dd] - mean) * rs * og[i * 128 + dd] + ob[i * 128 + dd]) * sil;
    }
    int src = (i + h % 3 + w % 3) % 3;
    const float* fe = ws + OFF_FE + (size_t)(src * B_ + b) * 64 * L_ + l;
    float* vo = ws + OFF_VSS + (size_t)ib * 64 * L_ + l;
    const float* wb = ow + (size_t)i * 64 * DI_;
    for (int c = 0; c < 64; ++c) {
        const float4* wr = (const float4*)(wb + c * DI_);
        float acc = obias[i * 64 + c];
#pragma unroll
        for (int j = 0; j < 32; ++j) {
            float4 wv = wr[j];
            acc = fmaf(y[j*4+0], wv.x, acc);
            acc = fmaf(y[j*4+1], wv.y, acc);
            acc = fmaf(y[j*4+2], wv.z, acc);
            acc = fmaf(y[j*4+3], wv.w, acc);
        }
        vo[(size_t)c * L_] = fe[(size_t)c * L_] + acc;
    }
}

// ---------------- stage 7: Q/V from v3, K1 from v1, K2 from v2 ----------------
__global__ void __launch_bounds__(256) pex_qkv(
    const float* __restrict__ qw, const float* __restrict__ qb,
    const float* __restrict__ vw, const float* __restrict__ vb,
    const float* __restrict__ k1w, const float* __restrict__ k1b,
    const float* __restrict__ k2w, const float* __restrict__ k2b,
    float* __restrict__ ws)
{
    int which = blockIdx.y;
    int bid = blockIdx.x;
    int b = bid >> 4;
    int l = (bid & 15) * 256 + threadIdx.x;
    int isrc = (which == 0) ? 2 : (which - 1);
    const float* vp = ws + OFF_VSS + (size_t)(isrc * B_ + b) * 64 * L_ + l;
    float f[64];
#pragma unroll
    for (int c = 0; c < 64; ++c) f[c] = vp[(size_t)c * L_];
    if (which == 0) {
        float* Qp = ws + OFF_Q + ((size_t)b * L_ + l) * 64;
        float* Vp = ws + OFF_V + ((size_t)b * L_ + l) * 64;
        for (int c = 0; c < 64; ++c) {
            const float4* wr = (const float4*)(qw + c * 64);
            float acc = qb[c];
#pragma unroll
            for (int j = 0; j < 16; ++j) {
                float4 w = wr[j];
                acc = fmaf(f[j*4+0], w.x, acc);
                acc = fmaf(f[j*4+1], w.y, acc);
                acc = fmaf(f[j*4+2], w.z, acc);
                acc = fmaf(f[j*4+3], w.w, acc);
            }
            Qp[c] = acc;
        }
        for (int c = 0; c < 64; ++c) {
            const float4* wr = (const float4*)(vw + c * 64);
            float acc = vb[c];
#pragma unroll
            for (int j = 0; j < 16; ++j) {
                float4 w = wr[j];
                acc = fmaf(f[j*4+0], w.x, acc);
                acc = fmaf(f[j*4+1], w.y, acc);
                acc = fmaf(f[j*4+2], w.z, acc);
                acc = fmaf(f[j*4+3], w.w, acc);
            }
            Vp[c] = acc;
        }
    } else {
        const float* kw = (which == 1) ? k1w : k2w;
        const float* kb = (which == 1) ? k1b : k2b;
        float* Kp = ws + ((which == 1) ? OFF_K1 : OFF_K2) + (size_t)b * 64 * L_ + l;
        for (int c = 0; c < 64; ++c) {
            const float4* wr = (const float4*)(kw + c * 64);
            float acc = kb[c];
#pragma unroll
            for (int j = 0; j < 16; ++j) {
                float4 w = wr[j];
                acc = fmaf(f[j*4+0], w.x, acc);
                acc = fmaf(f[j*4+1], w.y, acc);
                acc = fmaf(f[j*4+2], w.z, acc);
                acc = fmaf(f[j*4+3], w.w, acc);
            }
            Kp[(size_t)c * L_] = acc;
        }
    }
}

// ---------------- stage 8: flash-style attention ----------------
__global__ void __launch_bounds__(256) pex_attn(float* __restrict__ ws)
{
    __shared__ float Qs[64 * 68];
    __shared__ float Ks[64 * 68];   // reused as P tile
    __shared__ float Vs[64 * 68];
    int bid = blockIdx.x;
    int qt = bid & 63;
    int m  = (bid >> 6) & 1;
    int b  = bid >> 7;
    const float* Qg = ws + OFF_Q + ((size_t)b * L_ + qt * 64) * 64;
    const float* Kg = ws + (m ? OFF_K2 : OFF_K1) + (size_t)b * 64 * L_;
    const float* Vg = ws + OFF_V + (size_t)b * L_ * 64;
    float* Og = ws + (m ? OFF_O2 : OFF_O1) + ((size_t)b * L_ + qt * 64) * 64;
    int tid = threadIdx.x;
    int qb = tid >> 4, mb = tid & 15;
    int q0 = qb * 4, c0 = mb * 4;
#pragma unroll
    for (int j = 0; j < 4; ++j) {
        int e = j * 1024 + tid * 4;
        int row = e >> 6, col = e & 63;
        float4 qv = *(const float4*)&Qg[row * 64 + col];
        qv.x *= 0.125f; qv.y *= 0.125f; qv.z *= 0.125f; qv.w *= 0.125f;
        *(float4*)&Qs[row * 68 + col] = qv;
    }
    float acc[4][4];
    float mrun[4], lrun[4];
#pragma unroll
    for (int ii = 0; ii < 4; ++ii) {
        mrun[ii] = -INFINITY; lrun[ii] = 0.f;
#pragma unroll
        for (int jj = 0; jj < 4; ++jj) acc[ii][jj] = 0.f;
    }
    for (int kt = 0; kt < 64; ++kt) {
        int ko = kt * 64;
        __syncthreads();
#pragma unroll
        for (int j = 0; j < 4; ++j) {
            int e = j * 1024 + tid * 4;
            int row = e >> 6, col = e & 63;
            *(float4*)&Ks[row * 68 + col] = *(const float4*)&Kg[(size_t)row * L_ + ko + col];
            *(float4*)&Vs[row * 68 + col] = *(const float4*)&Vg[(size_t)(ko + row) * 64 + col];
        }
        __syncthreads();
        float s[4][4];
#pragma unroll
        for (int ii = 0; ii < 4; ++ii)
#pragma unroll
            for (int jj = 0; jj < 4; ++jj) s[ii][jj] = 0.f;
        for (int c = 0; c < 64; ++c) {
            float4 kv = *(const float4*)&Ks[c * 68 + c0];
            float a0 = Qs[(q0 + 0) * 68 + c];
            float a1 = Qs[(q0 + 1) * 68 + c];
            float a2 = Qs[(q0 + 2) * 68 + c];
            float a3 = Qs[(q0 + 3) * 68 + c];
            s[0][0] = fmaf(a0, kv.x, s[0][0]); s[0][1] = fmaf(a0, kv.y, s[0][1]);
            s[0][2] = fmaf(a0, kv.z, s[0][2]); s[0][3] = fmaf(a0, kv.w, s[0][3]);
            s[1][0] = fmaf(a1, kv.x, s[1][0]); s[1][1] = fmaf(a1, kv.y, s[1][1]);
            s[1][2] = fmaf(a1, kv.z, s[1][2]); s[1][3] = fmaf(a1, kv.w, s[1][3]);
            s[2][0] = fmaf(a2, kv.x, s[2][0]); s[2][1] = fmaf(a2, kv.y, s[2][1]);
            s[2][2] = fmaf(a2, kv.z, s[2][2]); s[2][3] = fmaf(a2, kv.w, s[2][3]);
            s[3][0] = fmaf(a3, kv.x, s[3][0]); s[3][1] = fmaf(a3, kv.y, s[3][1]);
            s[3][2] = fmaf(a3, kv.z, s[3][2]); s[3][3] = fmaf(a3, kv.w, s[3][3]);
        }
        __syncthreads();
        float pv[4][4];
#pragma unroll
        for (int ii = 0; ii < 4; ++ii) {
            float tm = fmaxf(fmaxf(s[ii][0], s[ii][1]), fmaxf(s[ii][2], s[ii][3]));
            tm = fmaxf(tm, __shfl_xor(tm, 1));
            tm = fmaxf(tm, __shfl_xor(tm, 2));
            tm = fmaxf(tm, __shfl_xor(tm, 4));
            tm = fmaxf(tm, __shfl_xor(tm, 8));
            float mn = fmaxf(mrun[ii], tm);
            float co = __expf(mrun[ii] - mn);
            float ts = 0.f;
#pragma unroll
            for (int jj = 0; jj < 4; ++jj) {
                float e2 = __expf(s[ii][jj] - mn);
                pv[ii][jj] = e2;
                ts += e2;
            }
            ts += __shfl_xor(ts, 1);
            ts += __shfl_xor(ts, 2);
            ts += __shfl_xor(ts, 4);
            ts += __shfl_xor(ts, 8);
            lrun[ii] = lrun[ii] * co + ts;
            mrun[ii] = mn;
#pragma unroll
            for (int jj = 0; jj < 4; ++jj) acc[ii][jj] *= co;
        }
#pragma unroll
        for (int ii = 0; ii < 4; ++ii)
            *(float4*)&Ks[(q0 + ii) * 68 + c0] =
                make_float4(pv[ii][0], pv[ii][1], pv[ii][2], pv[ii][3]);
        __syncthreads();
        for (int mm = 0; mm < 64; ++mm) {
            float4 vv = *(const float4*)&Vs[mm * 68 + c0];
            float p0 = Ks[(q0 + 0) * 68 + mm];
            float p1 = Ks[(q0 + 1) * 68 + mm];
            float p2 = Ks[(q0 + 2) * 68 + mm];
            float p3 = Ks[(q0 + 3) * 68 + mm];
            acc[0][0] = fmaf(p0, vv.x, acc[0][0]); acc[0][1] = fmaf(p0, vv.y, acc[0][1]);
            acc[0][2] = fmaf(p0, vv.z, acc[0][2]); acc[0][3] = fmaf(p0, vv.w, acc[0][3]);
            acc[1][0] = fmaf(p1, vv.x, acc[1][0]); acc[1][1] = fmaf(p1, vv.y, acc[1][1]);
            acc[1][2] = fmaf(p1, vv.z, acc[1][2]); acc[1][3] = fmaf(p1, vv.w, acc[1][3]);
            acc[2][0] = fmaf(p2, vv.x, acc[2][0]); acc[2][1] = fmaf(p2, vv.y, acc[2][1]);
            acc[2][2] = fmaf(p2, vv.z, acc[2][2]); acc[2][3] = fmaf(p2, vv.w, acc[2][3]);
            acc[3][0] = fmaf(p3, vv.x, acc[3][0]); acc[3][1] = fmaf(p3, vv.y, acc[3][1]);
            acc[3][2] = fmaf(p3, vv.z, acc[3][2]); acc[3][3] = fmaf(p3, vv.w, acc[3][3]);
        }
    }
#pragma unroll
    for (int ii = 0; ii < 4; ++ii) {
        float inv = 1.f / lrun[ii];
        *(float4*)&Og[(size_t)(q0 + ii) * 64 + c0] =
            make_float4(acc[ii][0] * inv, acc[ii][1] * inv, acc[ii][2] * inv, acc[ii][3] * inv);
    }
}

// ---------------- stage 9: proj over cat([O1+O2, v1, v2]) ----------------
__global__ void __launch_bounds__(256) pex_proj(
    const float* __restrict__ pbias, float* __restrict__ ws)
{
    int bid = blockIdx.x;
    int b = bid >> 4;
    int l = (bid & 15) * 256 + threadIdx.x;
    float acc[64];
#pragma unroll
    for (int c = 0; c < 64; ++c) acc[c] = pbias[c];
    const float* pwT = ws + OFF_PWT;
    const float4* o1 = (const float4*)(ws + OFF_O1 + ((size_t)b * L_ + l) * 64);
    const float4* o2 = (const float4*)(ws + OFF_O2 + ((size_t)b * L_ + l) * 64);
#pragma unroll
    for (int j = 0; j < 16; ++j) {
        float4 a = o1[j], d = o2[j];
        float v[4] = {a.x + d.x, a.y + d.y, a.z + d.z, a.w + d.w};
#pragma unroll
        for (int jj = 0; jj < 4; ++jj) {
            const float4* wr = (const float4*)(pwT + (j * 4 + jj) * 64);
#pragma unroll
            for (int u = 0; u < 16; ++u) {
                float4 w = wr[u];
                acc[u*4+0] = fmaf(v[jj], w.x, acc[u*4+0]);
                acc[u*4+1] = fmaf(v[jj], w.y, acc[u*4+1]);
                acc[u*4+2] = fmaf(v[jj], w.z, acc[u*4+2]);
                acc[u*4+3] = fmaf(v[jj], w.w, acc[u*4+3]);
            }
        }
    }
    for (int part = 0; part < 2; ++part) {
        const float* vp = ws + OFF_VSS + (size_t)(part * B_ + b) * 64 * L_ + l;
        for (int cc = 0; cc < 64; ++cc) {
            float v = vp[(size_t)cc * L_];
            const float4* wr = (const float4*)(pwT + (64 + part * 64 + cc) * 64);
#pragma unroll
            for (int u = 0; u < 16; ++u) {
                float4 w = wr[u];
                acc[u*4+0] = fmaf(v, w.x, acc[u*4+0]);
                acc[u*4+1] = fmaf(v, w.y, acc[u*4+1]);
                acc[u*4+2] = fmaf(v, w.z, acc[u*4+2]);
                acc[u*4+3] = fmaf(v, w.w, acc[u*4+3]);
            }
        }
    }
    float* rp = ws + OFF_RAW + (size_t)b * 64 * L_ + l;
#pragma unroll
    for (int c = 0; c < 64; ++c) rp[(size_t)c * L_] = acc[c];
}

// ---------------- stage 9b: per-channel BN stats ----------------
__global__ void __launch_bounds__(256) pex_stats(float* __restrict__ ws)
{
    int c = blockIdx.x;
    float s = 0.f, s2 = 0.f;
    for (int idx = threadIdx.x; idx < B_ * L_; idx += 256) {
        int b = idx >> 12;
        int l = idx & 4095;
        float v = ws[OFF_RAW + (size_t)(b * 64 + c) * L_ + l];
        s += v;
        s2 = fmaf(v, v, s2);
    }
    for (int off = 1; off < 64; off <<= 1) {
        s  += __shfl_xor(s, off);
        s2 += __shfl_xor(s2, off);
    }
    __shared__ float ps[8];
    int wid = threadIdx.x >> 6;
    if ((threadIdx.x & 63) == 0) { ps[wid] = s; ps[4 + wid] = s2; }
    __syncthreads();
    if (threadIdx.x == 0) {
        ws[OFF_ST + c]      = ps[0] + ps[1] + ps[2] + ps[3];
        ws[OFF_ST + 64 + c] = ps[4] + ps[5] + ps[6] + ps[7];
    }
}

// ---------------- stage 10: BN + ReLU ----------------
__global__ void __launch_bounds__(256) pex_bn(
    const float* __restrict__ bng, const float* __restrict__ bnb,
    float* __restrict__ out, const float* __restrict__ ws)
{
    int idx = blockIdx.x * 256 + threadIdx.x;     // (b*64+c)*4096 + l
    int c = (idx >> 12) & 63;
    float sum  = ws[OFF_ST + c];
    float sum2 = ws[OFF_ST + 64 + c];
    float mean = sum * (1.f / 8192.f);
    float var  = sum2 * (1.f / 8192.f) - mean * mean;
    float x = ws[OFF_RAW + idx];
    float y = (x - mean) * rsqrtf(var + 1e-5f) * bng[c] + bnb[c];
    out[idx] = fmaxf(y, 0.f);
}

extern "C" void kernel_launch(void* const* d_in, const int* in_sizes, int n_in,
                              void* d_out, int out_size, void* d_ws, size_t ws_size,
                              hipStream_t stream)
{
    (void)in_sizes; (void)n_in; (void)out_size; (void)ws_size;
    float* ws = (float*)d_ws;
    const float* x1      = (const float*)d_in[0];
    const float* x2      = (const float*)d_in[1];
    const float* x3      = (const float*)d_in[2];
    const float* aw1     = (const float*)d_in[3];
    const float* ab1     = (const float*)d_in[4];
    const float* aw2     = (const float*)d_in[5];
    const float* ab2     = (const float*)d_in[6];
    const float* aw3     = (const float*)d_in[7];
    const float* ab3     = (const float*)d_in[8];
    const float* ln_g    = (const float*)d_in[9];
    const float* ln_b    = (const float*)d_in[10];
    const float* in_w    = (const float*)d_in[11];
    const float* in_b    = (const float*)d_in[12];
    const float* conv_w  = (const float*)d_in[13];
    const float* conv_b  = (const float*)d_in[14];
    const float* xproj_w = (const float*)d_in[15];
    const float* dt_w    = (const float*)d_in[16];
    const float* dt_b    = (const float*)d_in[17];
    const float* A_log   = (const float*)d_in[18];
    const float* Ds      = (const float*)d_in[19];
    const float* onorm_g = (const float*)d_in[20];
    const float* onorm_b = (const float*)d_in[21];
    const float* out_w   = (const float*)d_in[22];
    const float* out_b   = (const float*)d_in[23];
    const float* k1_w    = (const float*)d_in[24];
    const float* k1_b    = (const float*)d_in[25];
    const float* k2_w    = (const float*)d_in[26];
    const float* k2_b    = (const float*)d_in[27];
    const float* q3_w    = (const float*)d_in[28];
    const float* q3_b    = (const float*)d_in[29];
    const float* v3_w    = (const float*)d_in[30];
    const float* v3_b    = (const float*)d_in[31];
    const float* proj_w  = (const float*)d_in[32];
    const float* proj_b  = (const float*)d_in[33];
    const float* bn_g    = (const float*)d_in[34];
    const float* bn_b    = (const float*)d_in[35];

    pex_prep  <<<128, 256, 0, stream>>>(aw1, aw2, aw3, proj_w, ws);
    pex_feats <<<dim3(96, 2), 256, 0, stream>>>(x1, x2, x3, ab1, ab2, ab3, ws);
    pex_lnproj<<<dim3(96, 2), 256, 0, stream>>>(ln_g, ln_b, in_w, in_b, ws);
    pex_conv  <<<768, 256, 0, stream>>>(conv_w, conv_b, ws);
    pex_bct   <<<384, 256, 0, stream>>>(xproj_w, ws);
    // zero the Y accumulator (aliases XC, which is dead after pex_conv)
    hipMemsetAsync(ws + OFF_Y, 0, 3145728 * sizeof(float), stream);
    pex_scan1 <<<dim3(48, NCHUNK), 1024, 0, stream>>>(dt_w, dt_b, A_log, ws);
    pex_scan2 <<<192, 256, 0, stream>>>(ws);
    pex_scan3 <<<dim3(48, NCHUNK), 1024, 0, stream>>>(dt_w, dt_b, A_log, Ds, ws);
    pex_comb  <<<96, 256, 0, stream>>>(onorm_g, onorm_b, out_w, out_b, ws);
    pex_qkv   <<<dim3(32, 3), 256, 0, stream>>>(q3_w, q3_b, v3_w, v3_b, k1_w, k1_b, k2_w, k2_b, ws);
    pex_attn  <<<256, 256, 0, stream>>>(ws);
    pex_proj  <<<32, 256, 0, stream>>>(proj_b, ws);
    pex_stats <<<64, 256, 0, stream>>>(ws);
    pex_bn    <<<2048, 256, 0, stream>>>(bn_g, bn_b, (float*)d_out, ws);
}

// Round 3
// 1270.641 us; speedup vs baseline: 4.1050x; 1.2065x over previous
//
#include <hip/hip_runtime.h>
#include <math.h>

// Problem constants
#define B_   2
#define L_   4096
#define DI_  128
#define NCHUNK 32
#define TCHUNK 128   // L_/NCHUNK

// -------- workspace layout (float offsets), stage-lifetime aliased --------
static constexpr size_t OFF_XC   = 0;           // 3,145,728
static constexpr size_t OFF_Y    = 0;           // 3,145,728
static constexpr size_t OFF_XC2  = 3145728;     // 3,145,728 (conv->scan3); VSS aliases after
static constexpr size_t OFF_XC2T = 6291456;     // 3,145,728 (conv->scan3); QKV bf16 + O alias after
static constexpr size_t OFF_BC   = 9437184;     // 24*4096*36 = 3,538,944 (bct->scan3); RAW aliases after
static constexpr size_t OFF_SCA  = 12976128;    // 48*32*1024 = 1,572,864
static constexpr size_t OFF_SCB  = 14548992;    // 1,572,864
static constexpr size_t OFF_FE   = 16121856;    // 1,572,864 (feats->comb)
static constexpr size_t OFF_Z    = 17694720;    // 3,145,728 (lnproj->comb)
static constexpr size_t OFF_AWT1 = 20840448;    // 8192
static constexpr size_t OFF_AWT2 = 20848640;    // 16384
static constexpr size_t OFF_AWT3 = 20865024;    // 32768
static constexpr size_t OFF_PWT  = 20897792;    // 12288
// post-scan aliases:
static constexpr size_t OFF_VSS  = 3145728;     // over XC2 (comb->proj)
// bf16 QKV buffers live over XC2T; offsets in ushort units relative to (ushort*)(ws+OFF_XC2T)
static constexpr size_t OFF_QB_U  = 0;          // [B][L][64] bf16
static constexpr size_t OFF_K1B_U = 524288;     // [B][L][64] bf16
static constexpr size_t OFF_K2B_U = 1048576;    // [B][L][64] bf16
static constexpr size_t OFF_VB_U  = 1572864;    // [B][64][L] bf16 (channel-major)
static constexpr size_t OFF_O1   = 7340032;     // fp32 [B][L][64] (XC2T float off + 1,048,576)
static constexpr size_t OFF_O2   = 7864320;
static constexpr size_t OFF_RAW  = 9437184;     // over BC (proj->bn)
static constexpr size_t OFF_ST   = 9961472;

using bf16x8 = __attribute__((ext_vector_type(8))) short;
using f32x4  = __attribute__((ext_vector_type(4))) float;

__device__ inline ushort f2bf(float x) {
    uint u = __float_as_uint(x);
    uint r = (u + 0x7fffu + ((u >> 16) & 1u)) >> 16;
    return (ushort)r;
}
__device__ inline uint pack2(float a, float b) {
    return (uint)f2bf(a) | ((uint)f2bf(b) << 16);
}

// ---------------- weight transposes ----------------
__global__ void __launch_bounds__(256) pex_prep(
    const float* __restrict__ aw1, const float* __restrict__ aw2,
    const float* __restrict__ aw3, const float* __restrict__ pw,
    float* __restrict__ ws)
{
    int idx = blockIdx.x * 256 + threadIdx.x;   // 32768 total
    int ic = idx >> 6, c = idx & 63;
    if (ic < 128) ws[OFF_AWT1 + idx] = aw1[c * 128 + ic];
    if (ic < 256) ws[OFF_AWT2 + idx] = aw2[c * 256 + ic];
    ws[OFF_AWT3 + idx] = aw3[c * 512 + ic];
    if (idx < 192 * 64) {
        int cp = idx >> 6;
        ws[OFF_PWT + idx] = pw[c * 192 + cp];
    }
}

// ---------------- stage 1: feats = conv1x1(x_i) ----------------
__global__ void __launch_bounds__(256) pex_feats(
    const float* __restrict__ x1, const float* __restrict__ x2, const float* __restrict__ x3,
    const float* __restrict__ ab1, const float* __restrict__ ab2, const float* __restrict__ ab3,
    float* __restrict__ ws)
{
    int bid = blockIdx.x;            // i*32 + b*16 + pt
    int i = bid >> 5;
    int r = bid & 31;
    int b = r >> 4;
    int p = (r & 15) * 256 + threadIdx.x;
    int c0 = blockIdx.y * 32;
    const float* xp; const float* ab; const float* awT; int IC;
    if (i == 0)      { xp = x1; ab = ab1; awT = ws + OFF_AWT1; IC = 128; }
    else if (i == 1) { xp = x2; ab = ab2; awT = ws + OFF_AWT2; IC = 256; }
    else             { xp = x3; ab = ab3; awT = ws + OFF_AWT3; IC = 512; }
    xp += (size_t)b * IC * L_ + p;
    float acc[32];
#pragma unroll
    for (int c = 0; c < 32; ++c) acc[c] = ab[c0 + c];
    for (int ic = 0; ic < IC; ++ic) {
        float v = xp[(size_t)ic * L_];
        const float4* wr = (const float4*)(awT + ic * 64 + c0);
#pragma unroll
        for (int j = 0; j < 8; ++j) {
            float4 w = wr[j];
            acc[j*4+0] = fmaf(v, w.x, acc[j*4+0]);
            acc[j*4+1] = fmaf(v, w.y, acc[j*4+1]);
            acc[j*4+2] = fmaf(v, w.z, acc[j*4+2]);
            acc[j*4+3] = fmaf(v, w.w, acc[j*4+3]);
        }
    }
    float* fe = ws + OFF_FE + ((size_t)(i * B_ + b) * 64 + c0) * L_ + p;
#pragma unroll
    for (int c = 0; c < 32; ++c) fe[(size_t)c * L_] = acc[c];
}

// ---------------- stage 2: pixel-exchange gather + LN + in_proj ----------------
__global__ void __launch_bounds__(256) pex_lnproj(
    const float* __restrict__ lng, const float* __restrict__ lnb,
    const float* __restrict__ inw, const float* __restrict__ inb,
    float* __restrict__ ws)
{
    int bid = blockIdx.x;
    int i = bid >> 5;
    int r = bid & 31;
    int b = r >> 4;
    int p = (r & 15) * 256 + threadIdx.x;
    int h = p >> 6, w = p & 63;
    int src = (i + h % 3 + w % 3) % 3;
    const float* fe = ws + OFF_FE + (size_t)(src * B_ + b) * 64 * L_ + p;
    float f[64];
    float s = 0.f;
#pragma unroll
    for (int c = 0; c < 64; ++c) { f[c] = fe[(size_t)c * L_]; s += f[c]; }
    float mean = s * (1.f / 64.f);
    float vs = 0.f;
#pragma unroll
    for (int c = 0; c < 64; ++c) { float d = f[c] - mean; vs = fmaf(d, d, vs); }
    float rs = rsqrtf(vs * (1.f / 64.f) + 1e-5f);
#pragma unroll
    for (int c = 0; c < 64; ++c)
        f[c] = (f[c] - mean) * rs * lng[i * 64 + c] + lnb[i * 64 + c];

    const float* wbase = inw + (size_t)i * 256 * 64;
    float* outp = (blockIdx.y == 0)
        ? (ws + OFF_XC + (size_t)(i * B_ + b) * DI_ * L_ + p)
        : (ws + OFF_Z  + (size_t)(i * B_ + b) * DI_ * L_ + p);
    int oc0 = blockIdx.y * 128;
    for (int oc = 0; oc < 128; ++oc) {
        int oca = oc0 + oc;
        const float4* wr = (const float4*)(wbase + oca * 64);
        float acc = inb[i * 256 + oca];
#pragma unroll
        for (int j = 0; j < 16; ++j) {
            float4 w = wr[j];
            acc = fmaf(f[j*4+0], w.x, acc);
            acc = fmaf(f[j*4+1], w.y, acc);
            acc = fmaf(f[j*4+2], w.z, acc);
            acc = fmaf(f[j*4+3], w.w, acc);
        }
        outp[(size_t)oc * L_] = acc;
    }
}

// ---------------- stage 3: depthwise 3x3 conv + SiLU ----------------
__global__ void __launch_bounds__(256) pex_conv(
    const float* __restrict__ cw, const float* __restrict__ cb, float* __restrict__ ws)
{
    __shared__ float sm[64 * 65];
    int bid = blockIdx.x;          // i*256 + b*128 + d
    int i = bid >> 8;
    int r = bid & 255;
    int b = r >> 7;
    int d = r & 127;
    float wk[9];
#pragma unroll
    for (int j = 0; j < 9; ++j) wk[j] = cw[(size_t)(i * DI_ + d) * 9 + j];
    float bias = cb[i * DI_ + d];
    const float* xin = ws + OFF_XC + ((size_t)(i * B_ + b) * DI_ + d) * L_;
    float* xo  = ws + OFF_XC2  + ((size_t)(i * B_ + b) * DI_ + d) * L_;
    float* xoT = ws + OFF_XC2T + ((size_t)(i * B_ + b) * DI_ + d) * L_;
#pragma unroll
    for (int j = 0; j < 16; ++j) {
        int p = j * 256 + threadIdx.x;
        int h = p >> 6, w = p & 63;
        float acc = bias;
#pragma unroll
        for (int dh = 0; dh < 3; ++dh) {
            int hh = h + dh - 1;
            if (hh < 0 || hh > 63) continue;
#pragma unroll
            for (int dw = 0; dw < 3; ++dw) {
                int ww = w + dw - 1;
                if (ww < 0 || ww > 63) continue;
                acc = fmaf(xin[hh * 64 + ww], wk[dh * 3 + dw], acc);
            }
        }
        float v = acc / (1.f + __expf(-acc));
        xo[p] = v;
        sm[h * 65 + w] = v;
    }
    __syncthreads();
#pragma unroll
    for (int j = 0; j < 16; ++j) {
        int q = j * 256 + threadIdx.x;
        int h = q & 63, w = q >> 6;       // q = w*64 + h
        xoT[q] = sm[h * 65 + w];
    }
}

// ---------------- stage 4: x_dbl -> bc_t (r[4], B[16], C[16]) ----------------
__global__ void __launch_bounds__(256) pex_bct(
    const float* __restrict__ xpw, float* __restrict__ ws)
{
    int bid = blockIdx.x;            // ibk*16 + tt
    int tt = bid & 15;
    int ibk = bid >> 4;              // (i*B+b)*4 + k
    int k = ibk & 3;
    int ib = ibk >> 2;
    int i = ib >> 1;
    int t = tt * 256 + threadIdx.x;
    int ks = k & 1;
    int tx = (k >= 2) ? (L_ - 1 - t) : t;
    const float* xb = ws + (ks ? OFF_XC2T : OFF_XC2) + (size_t)ib * DI_ * L_ + tx;
    float xv[DI_];
#pragma unroll
    for (int dd = 0; dd < DI_; ++dd) xv[dd] = xb[(size_t)dd * L_];
    float* out = ws + OFF_BC + ((size_t)ibk * L_ + t) * 36;
    const float* wb = xpw + (size_t)(i * 4 + k) * 36 * DI_;
    for (int c = 0; c < 36; ++c) {
        const float4* wr = (const float4*)(wb + c * DI_);
        float acc = 0.f;
#pragma unroll
        for (int j = 0; j < 32; ++j) {
            float4 w = wr[j];
            acc = fmaf(xv[4*j+0], w.x, acc);
            acc = fmaf(xv[4*j+1], w.y, acc);
            acc = fmaf(xv[4*j+2], w.z, acc);
            acc = fmaf(xv[4*j+3], w.w, acc);
        }
        out[c] = acc;
    }
}

// ---------------- stage 5a: per-chunk (A_prod, B_local) ----------------
__global__ void __launch_bounds__(1024) pex_scan1(
    const float* __restrict__ dtw, const float* __restrict__ dtb,
    const float* __restrict__ Alog, float* __restrict__ ws)
{
    int grp = blockIdx.x;            // ibk*2 + dh
    int chunk = blockIdx.y;
    int dh = grp & 1;
    int ibk = grp >> 1;
    int k = ibk & 3;
    int ib = ibk >> 2;
    int i = ib >> 1;
    int tid = threadIdx.x;
    int dl = tid >> 4, n = tid & 15;
    int d = dh * 64 + dl;
    int ks = k & 1;
    bool rev = (k >= 2);
    int pidx = (i * 4 + k) * DI_ + d;
    float A  = -__expf(Alog[(size_t)pidx * 16 + n]);
    float w0 = dtw[(size_t)pidx * 4 + 0];
    float w1 = dtw[(size_t)pidx * 4 + 1];
    float w2 = dtw[(size_t)pidx * 4 + 2];
    float w3 = dtw[(size_t)pidx * 4 + 3];
    float db = dtb[pidx];
    const float* xb  = ws + (ks ? OFF_XC2T : OFF_XC2) + ((size_t)ib * DI_ + d) * L_;
    const float* bcb = ws + OFF_BC + (size_t)ibk * L_ * 36;
    float h = 0.f, ap = 1.f;
    int t0 = chunk * TCHUNK;
#pragma unroll 4
    for (int tt = 0; tt < TCHUNK; ++tt) {
        int t = t0 + tt;
        int tx = rev ? (L_ - 1 - t) : t;
        const float* bp = bcb + (size_t)t * 36;
        float4 rv = *(const float4*)bp;
        float Bv = bp[4 + n];
        float x = xb[tx];
        float dtr = fmaf(rv.x, w0, fmaf(rv.y, w1, fmaf(rv.z, w2, fmaf(rv.w, w3, db))));
        float dt = (dtr > 20.f) ? dtr : __logf(1.f + __expf(dtr));
        float dA = __expf(dt * A);
        h = fmaf(dA, h, dt * x * Bv);
        ap *= dA;
    }
    size_t o = ((size_t)grp * NCHUNK + chunk) * 1024 + tid;
    ws[OFF_SCA + o] = ap;
    ws[OFF_SCB + o] = h;
}

// ---------------- stage 5b: compose chunk prefixes ----------------
__global__ void __launch_bounds__(256) pex_scan2(float* __restrict__ ws)
{
    int chain = blockIdx.x * 256 + threadIdx.x;   // 49152 chains
    int grp = chain >> 10;
    int lane = chain & 1023;
    float h = 0.f;
    for (int c = 0; c < NCHUNK; ++c) {
        size_t o = ((size_t)grp * NCHUNK + c) * 1024 + lane;
        float a = ws[OFF_SCA + o];
        float b = ws[OFF_SCB + o];
        ws[OFF_SCA + o] = h;       // state at chunk start
        h = fmaf(a, h, b);
    }
}

// ---------------- stage 5c: re-run chunks with true h0 ----------------
__global__ void __launch_bounds__(1024) pex_scan3(
    const float* __restrict__ dtw, const float* __restrict__ dtb,
    const float* __restrict__ Alog, const float* __restrict__ Dsp,
    float* __restrict__ ws)
{
    int grp = blockIdx.x;
    int chunk = blockIdx.y;
    int dh = grp & 1;
    int ibk = grp >> 1;
    int k = ibk & 3;
    int ib = ibk >> 2;
    int i = ib >> 1;
    int tid = threadIdx.x;
    int dl = tid >> 4, n = tid & 15;
    int d = dh * 64 + dl;
    int ks = k & 1;
    bool rev = (k >= 2);
    int pidx = (i * 4 + k) * DI_ + d;
    float A  = -__expf(Alog[(size_t)pidx * 16 + n]);
    float w0 = dtw[(size_t)pidx * 4 + 0];
    float w1 = dtw[(size_t)pidx * 4 + 1];
    float w2 = dtw[(size_t)pidx * 4 + 2];
    float w3 = dtw[(size_t)pidx * 4 + 3];
    float db = dtb[pidx];
    float Dv = Dsp[pidx];
    const float* xb  = ws + (ks ? OFF_XC2T : OFF_XC2) + ((size_t)ib * DI_ + d) * L_;
    const float* bcb = ws + OFF_BC + (size_t)ibk * L_ * 36;
    float* yb = ws + OFF_Y + (size_t)ib * L_ * DI_ + d;
    float h = ws[OFF_SCA + ((size_t)grp * NCHUNK + chunk) * 1024 + tid];
    int t0 = chunk * TCHUNK;
#pragma unroll 2
    for (int tt = 0; tt < TCHUNK; ++tt) {
        int t = t0 + tt;
        int tx = rev ? (L_ - 1 - t) : t;
        const float* bp = bcb + (size_t)t * 36;
        float4 rv = *(const float4*)bp;
        float Bv = bp[4 + n];
        float Cv = bp[20 + n];
        float x = xb[tx];
        float dtr = fmaf(rv.x, w0, fmaf(rv.y, w1, fmaf(rv.z, w2, fmaf(rv.w, w3, db))));
        float dt = (dtr > 20.f) ? dtr : __logf(1.f + __expf(dtr));
        float dA = __expf(dt * A);
        h = fmaf(dA, h, dt * x * Bv);
        float p = h * Cv;
        p += __shfl_xor(p, 1);
        p += __shfl_xor(p, 2);
        p += __shfl_xor(p, 4);
        p += __shfl_xor(p, 8);
        if (n == 0) {
            int u = tx;
            int l = ks ? ((u & 63) * 64 + (u >> 6)) : u;
            atomicAdd(&yb[(size_t)l * DI_], fmaf(Dv, x, p));
        }
    }
}

// ---------------- stage 6: out-LN + silu(z) gate + out_proj + residual ----------------
__global__ void __launch_bounds__(256) pex_comb(
    const float* __restrict__ og, const float* __restrict__ ob,
    const float* __restrict__ ow, const float* __restrict__ obias,
    float* __restrict__ ws)
{
    int bid = blockIdx.x;
    int i = bid >> 5;
    int r = bid & 31;
    int b = r >> 4;
    int l = (r & 15) * 256 + threadIdx.x;
    int h = l >> 6, w = l & 63;
    int ib = i * B_ + b;
    const float4* yp = (const float4*)(ws + OFF_Y + ((size_t)ib * L_ + l) * DI_);
    float y[128];
    float s = 0.f;
#pragma unroll
    for (int j = 0; j < 32; ++j) {
        float4 a = yp[j];
        y[j*4+0] = a.x; y[j*4+1] = a.y; y[j*4+2] = a.z; y[j*4+3] = a.w;
        s += (a.x + a.y) + (a.z + a.w);
    }
    float mean = s * (1.f / 128.f);
    float vs = 0.f;
#pragma unroll
    for (int dd = 0; dd < 128; ++dd) { float t = y[dd] - mean; vs = fmaf(t, t, vs); }
    float rs = rsqrtf(vs * (1.f / 128.f) + 1e-5f);
    const float* zp = ws + OFF_Z + (size_t)ib * DI_ * L_ + l;
#pragma unroll
    for (int dd = 0; dd < 128; ++dd) {
        float zv = zp[(size_t)dd * L_];
        float sil = zv / (1.f + __expf(-zv));
        y[dd] = ((y[dd] - mean) * rs * og[i * 128 + dd] + ob[i * 128 + dd]) * sil;
    }
    int src = (i + h % 3 + w % 3) % 3;
    const float* fe = ws + OFF_FE + (size_t)(src * B_ + b) * 64 * L_ + l;
    float* vo = ws + OFF_VSS + (size_t)ib * 64 * L_ + l;
    const float* wb = ow + (size_t)i * 64 * DI_;
    for (int c = 0; c < 64; ++c) {
        const float4* wr = (const float4*)(wb + c * DI_);
        float acc = obias[i * 64 + c];
#pragma unroll
        for (int j = 0; j < 32; ++j) {
            float4 wv = wr[j];
            acc = fmaf(y[j*4+0], wv.x, acc);
            acc = fmaf(y[j*4+1], wv.y, acc);
            acc = fmaf(y[j*4+2], wv.z, acc);
            acc = fmaf(y[j*4+3], wv.w, acc);
        }
        vo[(size_t)c * L_] = fe[(size_t)c * L_] + acc;
    }
}

// ---------------- stage 7: Q/K1/K2 bf16 row-major, V bf16 channel-major ----------------
__global__ void __launch_bounds__(256) pex_qkv(
    const float* __restrict__ qw, const float* __restrict__ qb,
    const float* __restrict__ vw, const float* __restrict__ vb,
    const float* __restrict__ k1w, const float* __restrict__ k1b,
    const float* __restrict__ k2w, const float* __restrict__ k2b,
    float* __restrict__ ws)
{
    int which = blockIdx.y;
    int bid = blockIdx.x;
    int b = bid >> 4;
    int l = (bid & 15) * 256 + threadIdx.x;
    int isrc = (which == 0) ? 2 : (which - 1);
    const float* vp = ws + OFF_VSS + (size_t)(isrc * B_ + b) * 64 * L_ + l;
    float f[64];
#pragma unroll
    for (int c = 0; c < 64; ++c) f[c] = vp[(size_t)c * L_];
    ushort* qkvb = (ushort*)(ws + OFF_XC2T);
    if (which == 0) {
        // Q row-major bf16
        ushort* Qp = qkvb + OFF_QB_U + ((size_t)b * L_ + l) * 64;
#pragma unroll
        for (int g = 0; g < 8; ++g) {
            float o[8];
#pragma unroll
            for (int jj = 0; jj < 8; ++jj) {
                int c = g * 8 + jj;
                const float4* wr = (const float4*)(qw + c * 64);
                float acc = qb[c];
#pragma unroll
                for (int j = 0; j < 16; ++j) {
                    float4 w = wr[j];
                    acc = fmaf(f[j*4+0], w.x, acc);
                    acc = fmaf(f[j*4+1], w.y, acc);
                    acc = fmaf(f[j*4+2], w.z, acc);
                    acc = fmaf(f[j*4+3], w.w, acc);
                }
                o[jj] = acc;
            }
            uint4 u;
            u.x = pack2(o[0], o[1]); u.y = pack2(o[2], o[3]);
            u.z = pack2(o[4], o[5]); u.w = pack2(o[6], o[7]);
            *(uint4*)&Qp[g * 8] = u;
        }
        // V channel-major bf16 (coalesced stores)
        ushort* Vp = qkvb + OFF_VB_U + (size_t)b * 64 * L_ + l;
        for (int c = 0; c < 64; ++c) {
            const float4* wr = (const float4*)(vw + c * 64);
            float acc = vb[c];
#pragma unroll
            for (int j = 0; j < 16; ++j) {
                float4 w = wr[j];
                acc = fmaf(f[j*4+0], w.x, acc);
                acc = fmaf(f[j*4+1], w.y, acc);
                acc = fmaf(f[j*4+2], w.z, acc);
                acc = fmaf(f[j*4+3], w.w, acc);
            }
            Vp[(size_t)c * L_] = f2bf(acc);
        }
    } else {
        const float* kw = (which == 1) ? k1w : k2w;
        const float* kb = (which == 1) ? k1b : k2b;
        ushort* Kp = qkvb + ((which == 1) ? OFF_K1B_U : OFF_K2B_U) + ((size_t)b * L_ + l) * 64;
#pragma unroll
        for (int g = 0; g < 8; ++g) {
            float o[8];
#pragma unroll
            for (int jj = 0; jj < 8; ++jj) {
                int c = g * 8 + jj;
                const float4* wr = (const float4*)(kw + c * 64);
                float acc = kb[c];
#pragma unroll
                for (int j = 0; j < 16; ++j) {
                    float4 w = wr[j];
                    acc = fmaf(f[j*4+0], w.x, acc);
                    acc = fmaf(f[j*4+1], w.y, acc);
                    acc = fmaf(f[j*4+2], w.z, acc);
                    acc = fmaf(f[j*4+3], w.w, acc);
                }
                o[jj] = acc;
            }
            uint4 u;
            u.x = pack2(o[0], o[1]); u.y = pack2(o[2], o[3]);
            u.z = pack2(o[4], o[5]); u.w = pack2(o[6], o[7]);
            *(uint4*)&Kp[g * 8] = u;
        }
    }
}

// ---------------- stage 8: bf16 MFMA flash attention ----------------
// grid = B_*128 blocks (32 q-rows each), 256 threads = 4 waves.
// waves 0,1 -> map0 (K1), waves 2,3 -> map1 (K2). K1/K2/V^T tiles shared in LDS.
__global__ void __launch_bounds__(256) pex_attn(float* __restrict__ ws)
{
    __shared__ ushort Ksm[2][64 * 72];   // [map][key][ch], rows padded to 72
    __shared__ ushort Vtm[64 * 72];      // [ch][key]
    __shared__ ushort Psm[4][16 * 72];   // per-wave P tile [qrow][key]
    const ushort* qkvb = (const ushort*)(ws + OFF_XC2T);
    int bid = blockIdx.x;
    int qt = bid & 127;
    int b  = bid >> 7;
    const ushort* Qg  = qkvb + OFF_QB_U  + ((size_t)b * L_ + qt * 32) * 64;
    const ushort* K1g = qkvb + OFF_K1B_U + (size_t)b * L_ * 64;
    const ushort* K2g = qkvb + OFF_K2B_U + (size_t)b * L_ * 64;
    const ushort* Vg  = qkvb + OFF_VB_U  + (size_t)b * 64 * L_;
    int tid = threadIdx.x;
    int w = tid >> 6, l = tid & 63;
    int mp = w >> 1, wsub = w & 1;
    int lg = l >> 4, lr = l & 15;
    // Q A-fragments (row = lr within this wave's 16-row strip, k = lg*8..+8)
    bf16x8 qf0 = *(const bf16x8*)&Qg[(size_t)(wsub * 16 + lr) * 64 + lg * 8];
    bf16x8 qf1 = *(const bf16x8*)&Qg[(size_t)(wsub * 16 + lr) * 64 + 32 + lg * 8];
    f32x4 acc[4];
    float mrun[4], lrun[4];
#pragma unroll
    for (int ct = 0; ct < 4; ++ct) acc[ct] = (f32x4){0.f, 0.f, 0.f, 0.f};
#pragma unroll
    for (int j = 0; j < 4; ++j) { mrun[j] = -INFINITY; lrun[j] = 0.f; }
    float* Og = ws + (mp ? OFF_O2 : OFF_O1) + ((size_t)b * L_ + qt * 32 + wsub * 16) * 64;
    ushort* Pw = Psm[w];

    for (int kt = 0; kt < 64; ++kt) {
        int ko = kt * 64;
        __syncthreads();     // prior reads of Ksm/Vtm complete
        // stage K1,K2,V^T tiles: 1536 16B-chunks over 256 threads
#pragma unroll
        for (int cc = 0; cc < 6; ++cc) {
            int c = cc * 256 + tid;
            int buf = c >> 9;
            int row = (c >> 3) & 63;
            int col = (c & 7) * 8;
            const ushort* src;
            ushort* dst;
            if (buf == 0)      { src = &K1g[(size_t)(ko + row) * 64 + col]; dst = &Ksm[0][row * 72 + col]; }
            else if (buf == 1) { src = &K2g[(size_t)(ko + row) * 64 + col]; dst = &Ksm[1][row * 72 + col]; }
            else               { src = &Vg[(size_t)row * L_ + ko + col];    dst = &Vtm[row * 72 + col]; }
            *(uint4*)dst = *(const uint4*)src;
        }
        __syncthreads();
        // S = Q K^T for this wave's map
        const ushort* Km = Ksm[mp];
        f32x4 s[4];
#pragma unroll
        for (int nt = 0; nt < 4; ++nt) {
            bf16x8 kf0 = *(const bf16x8*)&Km[(nt * 16 + lr) * 72 + lg * 8];
            bf16x8 kf1 = *(const bf16x8*)&Km[(nt * 16 + lr) * 72 + 32 + lg * 8];
            f32x4 z = (f32x4){0.f, 0.f, 0.f, 0.f};
            z = __builtin_amdgcn_mfma_f32_16x16x32_bf16(qf0, kf0, z, 0, 0, 0);
            z = __builtin_amdgcn_mfma_f32_16x16x32_bf16(qf1, kf1, z, 0, 0, 0);
            s[nt] = z;
        }
        // online softmax (rows = lg*4+j, shared across 16 lanes of group lg)
#pragma unroll
        for (int j = 0; j < 4; ++j) {
            float mx = fmaxf(fmaxf(s[0][j], s[1][j]), fmaxf(s[2][j], s[3][j])) * 0.125f;
            mx = fmaxf(mx, __shfl_xor(mx, 1));
            mx = fmaxf(mx, __shfl_xor(mx, 2));
            mx = fmaxf(mx, __shfl_xor(mx, 4));
            mx = fmaxf(mx, __shfl_xor(mx, 8));
            float mn = fmaxf(mrun[j], mx);
            float co = __expf(mrun[j] - mn);
            float ts = 0.f;
            float p0 = __expf(fmaf(s[0][j], 0.125f, -mn));
            float p1 = __expf(fmaf(s[1][j], 0.125f, -mn));
            float p2 = __expf(fmaf(s[2][j], 0.125f, -mn));
            float p3 = __expf(fmaf(s[3][j], 0.125f, -mn));
            ts = (p0 + p1) + (p2 + p3);
            ts += __shfl_xor(ts, 1);
            ts += __shfl_xor(ts, 2);
            ts += __shfl_xor(ts, 4);
            ts += __shfl_xor(ts, 8);
            lrun[j] = fmaf(lrun[j], co, ts);
            mrun[j] = mn;
            // write P row (q = lg*4+j) as bf16
            int rbase = (lg * 4 + j) * 72 + lr;
            Pw[rbase +  0] = f2bf(p0);
            Pw[rbase + 16] = f2bf(p1);
            Pw[rbase + 32] = f2bf(p2);
            Pw[rbase + 48] = f2bf(p3);
#pragma unroll
            for (int ct = 0; ct < 4; ++ct) acc[ct][j] *= co;
        }
        // O += P V  (A = P rows lr, B = V^T cols lr)
        bf16x8 pf0 = *(const bf16x8*)&Pw[lr * 72 + lg * 8];
        bf16x8 pf1 = *(const bf16x8*)&Pw[lr * 72 + 32 + lg * 8];
#pragma unroll
        for (int ct = 0; ct < 4; ++ct) {
            bf16x8 vf0 = *(const bf16x8*)&Vtm[(ct * 16 + lr) * 72 + lg * 8];
            bf16x8 vf1 = *(const bf16x8*)&Vtm[(ct * 16 + lr) * 72 + 32 + lg * 8];
            f32x4 o = acc[ct];
            o = __builtin_amdgcn_mfma_f32_16x16x32_bf16(pf0, vf0, o, 0, 0, 0);
            o = __builtin_amdgcn_mfma_f32_16x16x32_bf16(pf1, vf1, o, 0, 0, 0);
            acc[ct] = o;
        }
    }
#pragma unroll
    for (int j = 0; j < 4; ++j) {
        float inv = 1.f / lrun[j];
#pragma unroll
        for (int ct = 0; ct < 4; ++ct)
            Og[(size_t)(lg * 4 + j) * 64 + ct * 16 + lr] = acc[ct][j] * inv;
    }
}

// ---------------- stage 9: proj over cat([O1+O2, v1, v2]) ----------------
__global__ void __launch_bounds__(256) pex_proj(
    const float* __restrict__ pbias, float* __restrict__ ws)
{
    int bid = blockIdx.x;
    int b = bid >> 4;
    int l = (bid & 15) * 256 + threadIdx.x;
    float acc[64];
#pragma unroll
    for (int c = 0; c < 64; ++c) acc[c] = pbias[c];
    const float* pwT = ws + OFF_PWT;
    const float4* o1 = (const float4*)(ws + OFF_O1 + ((size_t)b * L_ + l) * 64);
    const float4* o2 = (const float4*)(ws + OFF_O2 + ((size_t)b * L_ + l) * 64);
#pragma unroll
    for (int j = 0; j < 16; ++j) {
        float4 a = o1[j], d = o2[j];
        float v[4] = {a.x + d.x, a.y + d.y, a.z + d.z, a.w + d.w};
#pragma unroll
        for (int jj = 0; jj < 4; ++jj) {
            const float4* wr = (const float4*)(pwT + (j * 4 + jj) * 64);
#pragma unroll
            for (int u = 0; u < 16; ++u) {
                float4 w = wr[u];
                acc[u*4+0] = fmaf(v[jj], w.x, acc[u*4+0]);
                acc[u*4+1] = fmaf(v[jj], w.y, acc[u*4+1]);
                acc[u*4+2] = fmaf(v[jj], w.z, acc[u*4+2]);
                acc[u*4+3] = fmaf(v[jj], w.w, acc[u*4+3]);
            }
        }
    }
    for (int part = 0; part < 2; ++part) {
        const float* vp = ws + OFF_VSS + (size_t)(part * B_ + b) * 64 * L_ + l;
        for (int cc = 0; cc < 64; ++cc) {
            float v = vp[(size_t)cc * L_];
            const float4* wr = (const float4*)(pwT + (64 + part * 64 + cc) * 64);
#pragma unroll
            for (int u = 0; u < 16; ++u) {
                float4 w = wr[u];
                acc[u*4+0] = fmaf(v, w.x, acc[u*4+0]);
                acc[u*4+1] = fmaf(v, w.y, acc[u*4+1]);
                acc[u*4+2] = fmaf(v, w.z, acc[u*4+2]);
                acc[u*4+3] = fmaf(v, w.w, acc[u*4+3]);
            }
        }
    }
    float* rp = ws + OFF_RAW + (size_t)b * 64 * L_ + l;
#pragma unroll
    for (int c = 0; c < 64; ++c) rp[(size_t)c * L_] = acc[c];
}

// ---------------- stage 9b: per-channel BN stats ----------------
__global__ void __launch_bounds__(256) pex_stats(float* __restrict__ ws)
{
    int c = blockIdx.x;
    float s = 0.f, s2 = 0.f;
    for (int idx = threadIdx.x; idx < B_ * L_; idx += 256) {
        int b = idx >> 12;
        int l = idx & 4095;
        float v = ws[OFF_RAW + (size_t)(b * 64 + c) * L_ + l];
        s += v;
        s2 = fmaf(v, v, s2);
    }
    for (int off = 1; off < 64; off <<= 1) {
        s  += __shfl_xor(s, off);
        s2 += __shfl_xor(s2, off);
    }
    __shared__ float ps[8];
    int wid = threadIdx.x >> 6;
    if ((threadIdx.x & 63) == 0) { ps[wid] = s; ps[4 + wid] = s2; }
    __syncthreads();
    if (threadIdx.x == 0) {
        ws[OFF_ST + c]      = ps[0] + ps[1] + ps[2] + ps[3];
        ws[OFF_ST + 64 + c] = ps[4] + ps[5] + ps[6] + ps[7];
    }
}

// ---------------- stage 10: BN + ReLU ----------------
__global__ void __launch_bounds__(256) pex_bn(
    const float* __restrict__ bng, const float* __restrict__ bnb,
    float* __restrict__ out, const float* __restrict__ ws)
{
    int idx = blockIdx.x * 256 + threadIdx.x;     // (b*64+c)*4096 + l
    int c = (idx >> 12) & 63;
    float sum  = ws[OFF_ST + c];
    float sum2 = ws[OFF_ST + 64 + c];
    float mean = sum * (1.f / 8192.f);
    float var  = sum2 * (1.f / 8192.f) - mean * mean;
    float x = ws[OFF_RAW + idx];
    float y = (x - mean) * rsqrtf(var + 1e-5f) * bng[c] + bnb[c];
    out[idx] = fmaxf(y, 0.f);
}

extern "C" void kernel_launch(void* const* d_in, const int* in_sizes, int n_in,
                              void* d_out, int out_size, void* d_ws, size_t ws_size,
                              hipStream_t stream)
{
    (void)in_sizes; (void)n_in; (void)out_size; (void)ws_size;
    float* ws = (float*)d_ws;
    const float* x1      = (const float*)d_in[0];
    const float* x2      = (const float*)d_in[1];
    const float* x3      = (const float*)d_in[2];
    const float* aw1     = (const float*)d_in[3];
    const float* ab1     = (const float*)d_in[4];
    const float* aw2     = (const float*)d_in[5];
    const float* ab2     = (const float*)d_in[6];
    const float* aw3     = (const float*)d_in[7];
    const float* ab3     = (const float*)d_in[8];
    const float* ln_g    = (const float*)d_in[9];
    const float* ln_b    = (const float*)d_in[10];
    const float* in_w    = (const float*)d_in[11];
    const float* in_b    = (const float*)d_in[12];
    const float* conv_w  = (const float*)d_in[13];
    const float* conv_b  = (const float*)d_in[14];
    const float* xproj_w = (const float*)d_in[15];
    const float* dt_w    = (const float*)d_in[16];
    const float* dt_b    = (const float*)d_in[17];
    const float* A_log   = (const float*)d_in[18];
    const float* Ds      = (const float*)d_in[19];
    const float* onorm_g = (const float*)d_in[20];
    const float* onorm_b = (const float*)d_in[21];
    const float* out_w   = (const float*)d_in[22];
    const float* out_b   = (const float*)d_in[23];
    const float* k1_w    = (const float*)d_in[24];
    const float* k1_b    = (const float*)d_in[25];
    const float* k2_w    = (const float*)d_in[26];
    const float* k2_b    = (const float*)d_in[27];
    const float* q3_w    = (const float*)d_in[28];
    const float* q3_b    = (const float*)d_in[29];
    const float* v3_w    = (const float*)d_in[30];
    const float* v3_b    = (const float*)d_in[31];
    const float* proj_w  = (const float*)d_in[32];
    const float* proj_b  = (const float*)d_in[33];
    const float* bn_g    = (const float*)d_in[34];
    const float* bn_b    = (const float*)d_in[35];

    pex_prep  <<<128, 256, 0, stream>>>(aw1, aw2, aw3, proj_w, ws);
    pex_feats <<<dim3(96, 2), 256, 0, stream>>>(x1, x2, x3, ab1, ab2, ab3, ws);
    pex_lnproj<<<dim3(96, 2), 256, 0, stream>>>(ln_g, ln_b, in_w, in_b, ws);
    pex_conv  <<<768, 256, 0, stream>>>(conv_w, conv_b, ws);
    pex_bct   <<<384, 256, 0, stream>>>(xproj_w, ws);
    // zero the Y accumulator (aliases XC, dead after pex_conv)
    hipMemsetAsync(ws + OFF_Y, 0, 3145728 * sizeof(float), stream);
    pex_scan1 <<<dim3(48, NCHUNK), 1024, 0, stream>>>(dt_w, dt_b, A_log, ws);
    pex_scan2 <<<192, 256, 0, stream>>>(ws);
    pex_scan3 <<<dim3(48, NCHUNK), 1024, 0, stream>>>(dt_w, dt_b, A_log, Ds, ws);
    pex_comb  <<<96, 256, 0, stream>>>(onorm_g, onorm_b, out_w, out_b, ws);
    pex_qkv   <<<dim3(32, 3), 256, 0, stream>>>(q3_w, q3_b, v3_w, v3_b, k1_w, k1_b, k2_w, k2_b, ws);
    pex_attn  <<<256, 256, 0, stream>>>(ws);
    pex_proj  <<<32, 256, 0, stream>>>(proj_b, ws);
    pex_stats <<<64, 256, 0, stream>>>(ws);
    pex_bn    <<<2048, 256, 0, stream>>>(bn_g, bn_b, (float*)d_out, ws);
}